// Round 8
// baseline (293.195 us; speedup 1.0000x reference)
//
#include <hip/hip_runtime.h>
#include <math.h>

#define BATCH   4
#define SEQLEN  4096
#define NDIM    256
#define DINNER  512
#define DSTATE  16
#define M_ROWS  (BATCH*SEQLEN)   // 16384
#define CHUNK   64
#define NCHUNK  (SEQLEN/CHUNK)   // 64

typedef unsigned short u16;
typedef short short8 __attribute__((ext_vector_type(8)));
typedef float floatx4 __attribute__((ext_vector_type(4)));

__device__ __forceinline__ u16 f32_to_bf16(float f) {
    union { float f; unsigned u; } v; v.f = f;
    unsigned u = v.u;
    unsigned r = (u + 0x7FFFu + ((u >> 16) & 1u)) >> 16;
    return (u16)r;
}
__device__ __forceinline__ float bf16_to_f32(u16 h) {
    union { unsigned u; float f; } v; v.u = ((unsigned)h) << 16;
    return v.f;
}

// ---------------------------------------------------------------------------
// prep_x: x (M_ROWS x 256 fp32, row-major) -> Xhi/Xlo bf16 row-major.
// ---------------------------------------------------------------------------
__global__ __launch_bounds__(256)
void prep_x(const float* __restrict__ X, u16* __restrict__ Xhi,
            u16* __restrict__ Xlo) {
    const size_t t = (size_t)blockIdx.x * 256 + threadIdx.x;
    const float4 v = ((const float4*)X)[t];
    u16 h[4], l[4];
    const float* vf = (const float*)&v;
    #pragma unroll
    for (int i = 0; i < 4; i++) {
        h[i] = f32_to_bf16(vf[i]);
        l[i] = f32_to_bf16(vf[i] - bf16_to_f32(h[i]));
    }
    uint2 hp, lp;
    hp.x = (unsigned)h[0] | ((unsigned)h[1] << 16);
    hp.y = (unsigned)h[2] | ((unsigned)h[3] << 16);
    lp.x = (unsigned)l[0] | ((unsigned)l[1] << 16);
    lp.y = (unsigned)l[2] | ((unsigned)l[3] << 16);
    ((uint2*)Xhi)[t] = hp;
    ((uint2*)Xlo)[t] = lp;
}

// ---------------------------------------------------------------------------
// prep_w: W (K x N fp32) -> packed hi/lo bf16 in B-fragment order:
// out[((kb*4+q)*N + n)*8 + j] = W[(kb*32+q*8+j)*N + n].
// ---------------------------------------------------------------------------
template<int N, int LOGN>
__global__ __launch_bounds__(256)
void prep_w(const float* __restrict__ W, u16* __restrict__ Whi,
            u16* __restrict__ Wlo) {
    const int t = blockIdx.x * 256 + threadIdx.x;
    const int j  = t & 7;
    const int n  = (t >> 3) & (N - 1);
    const int q  = (t >> (3 + LOGN)) & 3;
    const int kb = t >> (5 + LOGN);
    const int k  = kb * 32 + q * 8 + j;
    const float v = W[(size_t)k * N + n];
    const u16 hi = f32_to_bf16(v);
    Whi[t] = hi;
    Wlo[t] = f32_to_bf16(v - bf16_to_f32(hi));
}

// ---------------------------------------------------------------------------
// prep_w_proj: pack [Wdt|Wb|Wc|zeros] (512 x 64 logical) into B-frag order.
// ---------------------------------------------------------------------------
__global__ __launch_bounds__(256)
void prep_w_proj(const float* __restrict__ Wdt, const float* __restrict__ Wb,
                 const float* __restrict__ Wc, u16* __restrict__ Whi,
                 u16* __restrict__ Wlo) {
    const int t = blockIdx.x * 256 + threadIdx.x;   // < 32768
    const int n  = (t >> 3) & 63;
    const int q  = (t >> 9) & 3;
    const int kb = t >> 11;
    const int k  = kb * 32 + q * 8 + (t & 7);
    float v;
    if      (n < 16) v = Wdt[(size_t)k * 16 + n];
    else if (n < 32) v = Wb [(size_t)k * 16 + (n - 16)];
    else if (n < 48) v = Wc [(size_t)k * 16 + (n - 32)];
    else             v = 0.f;
    const u16 hi = f32_to_bf16(v);
    Whi[t] = hi;
    Wlo[t] = f32_to_bf16(v - bf16_to_f32(hi));
}

// ---------------------------------------------------------------------------
// Split-bf16 MFMA GEMM, NO LDS: A-fragments loaded directly from global
// (row-major hi/lo; each frag = one 16B-aligned short8), B-fragments from
// packed weights. No barriers in the K-loop -> compiler pipelines freely.
// SILU=true: silu -> split bf16 U (cols<512) / G (cols>=512). Else fp32 out.
// ---------------------------------------------------------------------------
template<int NT, int KT, bool SILU>
__global__ __launch_bounds__(256)
void mfma_gemm(const u16* __restrict__ Ahi, const u16* __restrict__ Alo,
               const u16* __restrict__ Whi, const u16* __restrict__ Wlo,
               float* __restrict__ Ofp,
               u16* __restrict__ O1h, u16* __restrict__ O1l,
               u16* __restrict__ O2h, u16* __restrict__ O2l) {
    const int tid = threadIdx.x;
    const int lane = tid & 63;
    const int w  = tid >> 6;
    const int wm = w >> 1, wn = w & 1;
    const int n0 = blockIdx.x * 128;
    const int m0 = blockIdx.y * 128;
    const int l15 = lane & 15, q = lane >> 4;

    floatx4 acc[4][4];
    const floatx4 zero = {0.f, 0.f, 0.f, 0.f};
    #pragma unroll
    for (int i = 0; i < 4; i++)
        #pragma unroll
        for (int j = 0; j < 4; j++) acc[i][j] = zero;

    // per-lane A row base (row = m0 + wm*64 + mt*16 + l15, k = kb*32 + q*8)
    const size_t aRow = (size_t)(m0 + wm * 64 + l15) * KT + q * 8;
    const u16* aHi = Ahi + aRow;
    const u16* aLo = Alo + aRow;

    for (int kb = 0; kb < KT / 32; kb++) {
        short8 bh[4], bl[4], ah[4], al[4];
        #pragma unroll
        for (int mt = 0; mt < 4; mt++) {
            const size_t off = (size_t)(mt * 16) * KT + kb * 32;
            ah[mt] = *(const short8*)(aHi + off);
            al[mt] = *(const short8*)(aLo + off);
        }
        #pragma unroll
        for (int nt = 0; nt < 4; nt++) {
            const size_t off =
                ((size_t)((kb * 4 + q) * NT) + n0 + wn * 64 + nt * 16 + l15) * 8;
            bh[nt] = *(const short8*)(Whi + off);
            bl[nt] = *(const short8*)(Wlo + off);
        }
        #pragma unroll
        for (int mt = 0; mt < 4; mt++)
            #pragma unroll
            for (int nt = 0; nt < 4; nt++) {
                acc[mt][nt] = __builtin_amdgcn_mfma_f32_16x16x32_bf16(
                    ah[mt], bh[nt], acc[mt][nt], 0, 0, 0);
                acc[mt][nt] = __builtin_amdgcn_mfma_f32_16x16x32_bf16(
                    ah[mt], bl[nt], acc[mt][nt], 0, 0, 0);
                acc[mt][nt] = __builtin_amdgcn_mfma_f32_16x16x32_bf16(
                    al[mt], bh[nt], acc[mt][nt], 0, 0, 0);
            }
    }
    // epilogue: D col=lane&15, row=quad*4+reg  [verified m89/m91]
    #pragma unroll
    for (int mt = 0; mt < 4; mt++) {
        #pragma unroll
        for (int nt = 0; nt < 4; nt++) {
            const int col = n0 + wn * 64 + nt * 16 + l15;
            #pragma unroll
            for (int r = 0; r < 4; r++) {
                const int row = m0 + wm * 64 + mt * 16 + q * 4 + r;
                float v = acc[mt][nt][r];
                if (SILU) {
                    v = v / (1.f + __expf(-v));
                    const u16 hi = f32_to_bf16(v);
                    const u16 lo = f32_to_bf16(v - bf16_to_f32(hi));
                    if (col < DINNER) {
                        const size_t o = (size_t)row * DINNER + col;
                        O1h[o] = hi; O1l[o] = lo;
                    } else {
                        const size_t o = (size_t)row * DINNER + col - DINNER;
                        O2h[o] = hi; O2l[o] = lo;
                    }
                } else {
                    Ofp[(size_t)row * NT + col] = v;
                }
            }
        }
    }
}

// ---------------------------------------------------------------------------
// proj_mfma, NO LDS: U (split bf16) @ Wp (512x64 packed; 48 real cols) ->
// DT (softplus+bias) / BM / CM. 256 blocks x 64 rows, waves 2x2 of 32x32.
// ---------------------------------------------------------------------------
__global__ __launch_bounds__(256)
void proj_mfma(const u16* __restrict__ Uh, const u16* __restrict__ Ul,
               const u16* __restrict__ Whi, const u16* __restrict__ Wlo,
               const float* __restrict__ bias,
               float* __restrict__ DT, float* __restrict__ BM,
               float* __restrict__ CM) {
    const int tid = threadIdx.x;
    const int lane = tid & 63;
    const int w  = tid >> 6;
    const int wm = w >> 1, wn = w & 1;
    const int m0 = blockIdx.x * 64;
    const int l15 = lane & 15, q = lane >> 4;

    floatx4 acc[2][2];
    const floatx4 zero = {0.f, 0.f, 0.f, 0.f};
    #pragma unroll
    for (int i = 0; i < 2; i++)
        #pragma unroll
        for (int j = 0; j < 2; j++) acc[i][j] = zero;

    const size_t aRow = (size_t)(m0 + wm * 32 + l15) * DINNER + q * 8;
    const u16* aHi = Uh + aRow;
    const u16* aLo = Ul + aRow;

    for (int kb = 0; kb < DINNER / 32; kb++) {
        short8 bh[2], bl[2], ah[2], al[2];
        #pragma unroll
        for (int mt = 0; mt < 2; mt++) {
            const size_t off = (size_t)(mt * 16) * DINNER + kb * 32;
            ah[mt] = *(const short8*)(aHi + off);
            al[mt] = *(const short8*)(aLo + off);
        }
        #pragma unroll
        for (int nt = 0; nt < 2; nt++) {
            const size_t off =
                ((size_t)((kb * 4 + q) * 64) + wn * 32 + nt * 16 + l15) * 8;
            bh[nt] = *(const short8*)(Whi + off);
            bl[nt] = *(const short8*)(Wlo + off);
        }
        #pragma unroll
        for (int mt = 0; mt < 2; mt++)
            #pragma unroll
            for (int nt = 0; nt < 2; nt++) {
                acc[mt][nt] = __builtin_amdgcn_mfma_f32_16x16x32_bf16(
                    ah[mt], bh[nt], acc[mt][nt], 0, 0, 0);
                acc[mt][nt] = __builtin_amdgcn_mfma_f32_16x16x32_bf16(
                    ah[mt], bl[nt], acc[mt][nt], 0, 0, 0);
                acc[mt][nt] = __builtin_amdgcn_mfma_f32_16x16x32_bf16(
                    al[mt], bh[nt], acc[mt][nt], 0, 0, 0);
            }
    }
    #pragma unroll
    for (int mt = 0; mt < 2; mt++) {
        #pragma unroll
        for (int nt = 0; nt < 2; nt++) {
            const int col = wn * 32 + nt * 16 + l15;
            #pragma unroll
            for (int r = 0; r < 4; r++) {
                const int row = m0 + wm * 32 + mt * 16 + q * 4 + r;
                float v = acc[mt][nt][r];
                if (col < 16) {
                    float dv = v + bias[col];
                    dv = (dv > 20.f) ? dv : log1pf(__expf(dv));
                    DT[(size_t)row * 16 + col] = dv;
                } else if (col < 32) {
                    BM[(size_t)row * 16 + (col - 16)] = v;
                } else if (col < 48) {
                    CM[(size_t)row * 16 + (col - 32)] = v;
                }
            }
        }
    }
}

// ---------------------------------------------------------------------------
// K3a: chunked scan phase A. One thread per d; 16 states in registers.
// ---------------------------------------------------------------------------
__global__ __launch_bounds__(256)
void scan_phase_a(const float* __restrict__ DT, const float* __restrict__ BM,
                  const u16* __restrict__ Uh, const u16* __restrict__ Ul,
                  const float* __restrict__ Alog,
                  float* __restrict__ HEND, float* __restrict__ PPROD) {
    __shared__ float s_dt[CHUNK][DSTATE];
    __shared__ float s_db[CHUNK][DSTATE];
    const int tid = threadIdx.x;
    const int chunk = blockIdx.x;
    const int dg = blockIdx.y;
    const int b  = blockIdx.z;
    const int d  = dg*256 + tid;
    const int l0 = chunk * CHUNK;
    {
        const float4 dtv = ((const float4*)(DT + (size_t)(b*SEQLEN + l0)*16))[tid];
        const float4 bmv = ((const float4*)(BM + (size_t)(b*SEQLEN + l0)*16))[tid];
        ((float4*)&s_dt[0][0])[tid] = dtv;
        float4 dbv;
        dbv.x = dtv.x*bmv.x; dbv.y = dtv.y*bmv.y;
        dbv.z = dtv.z*bmv.z; dbv.w = dtv.w*bmv.w;
        ((float4*)&s_db[0][0])[tid] = dbv;
    }
    __syncthreads();
    float A[DSTATE];
    #pragma unroll
    for (int qq = 0; qq < 4; qq++) {
        const float4 av = ((const float4*)(Alog + (size_t)d*16))[qq];
        A[4*qq+0] = -__expf(av.x); A[4*qq+1] = -__expf(av.y);
        A[4*qq+2] = -__expf(av.z); A[4*qq+3] = -__expf(av.w);
    }
    float h[DSTATE] = {};
    float P[DSTATE];
    #pragma unroll
    for (int s = 0; s < DSTATE; s++) P[s] = 1.f;
    const u16* uhp = Uh + ((size_t)(b*SEQLEN + l0))*DINNER + d;
    const u16* ulp = Ul + ((size_t)(b*SEQLEN + l0))*DINNER + d;
    for (int l = 0; l < CHUNK; l++) {
        const float u = bf16_to_f32(uhp[(size_t)l*DINNER])
                      + bf16_to_f32(ulp[(size_t)l*DINNER]);
        #pragma unroll
        for (int s = 0; s < DSTATE; s++) {
            const float dA = __expf(s_dt[l][s] * A[s]);
            h[s] = dA*h[s] + s_db[l][s]*u;
            P[s] *= dA;
        }
    }
    float* he = HEND  + ((size_t)(b*NCHUNK + chunk)*DINNER + d)*16;
    float* pp = PPROD + ((size_t)(b*NCHUNK + chunk)*DINNER + d)*16;
    #pragma unroll
    for (int qq = 0; qq < 4; qq++) {
        float4 hv, pv;
        hv.x = h[4*qq+0]; hv.y = h[4*qq+1]; hv.z = h[4*qq+2]; hv.w = h[4*qq+3];
        pv.x = P[4*qq+0]; pv.y = P[4*qq+1]; pv.z = P[4*qq+2]; pv.w = P[4*qq+3];
        ((float4*)he)[qq] = hv;
        ((float4*)pp)[qq] = pv;
    }
}

// ---------------------------------------------------------------------------
// K3b: sequential chain over chunks. Thread per (b,d,s) = 32768.
// ---------------------------------------------------------------------------
__global__ __launch_bounds__(256)
void scan_phase_b(const float* __restrict__ HEND, const float* __restrict__ PPROD,
                  float* __restrict__ H0) {
    const int tid = threadIdx.x;
    const int s  = tid & 15;
    const int dl = tid >> 4;
    const int blk = blockIdx.x;
    const int b  = blk >> 5;
    const int dg = blk & 31;
    const int d  = dg*16 + dl;
    float h = 0.f;
    for (int c0 = 0; c0 < NCHUNK; c0 += 8) {
        float Pv[8], Hv[8];
        #pragma unroll
        for (int j = 0; j < 8; j++) {
            const size_t idx = ((size_t)(b*NCHUNK + c0 + j)*DINNER + d)*16 + s;
            Pv[j] = PPROD[idx];
            Hv[j] = HEND [idx];
        }
        #pragma unroll
        for (int j = 0; j < 8; j++) {
            H0[((size_t)(b*NCHUNK + c0 + j)*DINNER + d)*16 + s] = h;
            h = Pv[j]*h + Hv[j];
        }
    }
}

// ---------------------------------------------------------------------------
// K3c: rerun chunks from true initial state; u,g reconstructed from split
// bf16; emit Y2 as split bf16 hi/lo (feeds MFMA K4).
// ---------------------------------------------------------------------------
__global__ __launch_bounds__(256)
void scan_phase_c(const float* __restrict__ DT, const float* __restrict__ BM,
                  const float* __restrict__ CM,
                  const u16* __restrict__ Uh, const u16* __restrict__ Ul,
                  const u16* __restrict__ Gh, const u16* __restrict__ Gl,
                  const float* __restrict__ Alog,
                  const float* __restrict__ Dvec, const float* __restrict__ H0,
                  u16* __restrict__ Y2hi, u16* __restrict__ Y2lo) {
    __shared__ float s_dt[CHUNK][DSTATE];
    __shared__ float s_db[CHUNK][DSTATE];
    __shared__ float s_c [CHUNK][DSTATE];
    const int tid = threadIdx.x;
    const int chunk = blockIdx.x;
    const int dg = blockIdx.y;
    const int b  = blockIdx.z;
    const int d  = dg*256 + tid;
    const int l0 = chunk * CHUNK;
    {
        const float4 dtv = ((const float4*)(DT + (size_t)(b*SEQLEN + l0)*16))[tid];
        const float4 bmv = ((const float4*)(BM + (size_t)(b*SEQLEN + l0)*16))[tid];
        const float4 cmv = ((const float4*)(CM + (size_t)(b*SEQLEN + l0)*16))[tid];
        ((float4*)&s_dt[0][0])[tid] = dtv;
        float4 dbv;
        dbv.x = dtv.x*bmv.x; dbv.y = dtv.y*bmv.y;
        dbv.z = dtv.z*bmv.z; dbv.w = dtv.w*bmv.w;
        ((float4*)&s_db[0][0])[tid] = dbv;
        ((float4*)&s_c [0][0])[tid] = cmv;
    }
    __syncthreads();
    float A[DSTATE];
    #pragma unroll
    for (int qq = 0; qq < 4; qq++) {
        const float4 av = ((const float4*)(Alog + (size_t)d*16))[qq];
        A[4*qq+0] = -__expf(av.x); A[4*qq+1] = -__expf(av.y);
        A[4*qq+2] = -__expf(av.z); A[4*qq+3] = -__expf(av.w);
    }
    float h[DSTATE];
    {
        const float* h0 = H0 + ((size_t)(b*NCHUNK + chunk)*DINNER + d)*16;
        #pragma unroll
        for (int qq = 0; qq < 4; qq++) {
            const float4 hv = ((const float4*)h0)[qq];
            h[4*qq+0] = hv.x; h[4*qq+1] = hv.y; h[4*qq+2] = hv.z; h[4*qq+3] = hv.w;
        }
    }
    const float Dd = Dvec[d];
    const size_t base = ((size_t)(b*SEQLEN + l0))*DINNER + d;
    const u16* uhp = Uh + base;
    const u16* ulp = Ul + base;
    const u16* ghp = Gh + base;
    const u16* glp = Gl + base;
    u16* yhp = Y2hi + base;
    u16* ylp = Y2lo + base;
    for (int l = 0; l < CHUNK; l++) {
        const float u = bf16_to_f32(uhp[(size_t)l*DINNER])
                      + bf16_to_f32(ulp[(size_t)l*DINNER]);
        const float g = bf16_to_f32(ghp[(size_t)l*DINNER])
                      + bf16_to_f32(glp[(size_t)l*DINNER]);
        float y = 0.f;
        #pragma unroll
        for (int s = 0; s < DSTATE; s++) {
            const float dA = __expf(s_dt[l][s] * A[s]);
            h[s] = dA*h[s] + s_db[l][s]*u;
            y += h[s]*s_c[l][s];
        }
        const float yv = (y + u*Dd) * g;
        const u16 hi = f32_to_bf16(yv);
        yhp[(size_t)l*DINNER] = hi;
        ylp[(size_t)l*DINNER] = f32_to_bf16(yv - bf16_to_f32(hi));
    }
}

// ---------------------------------------------------------------------------
extern "C" void kernel_launch(void* const* d_in, const int* in_sizes, int n_in,
                              void* d_out, int out_size, void* d_ws, size_t ws_size,
                              hipStream_t stream) {
    const float* x        = (const float*)d_in[0];
    const float* x_proj   = (const float*)d_in[1];
    const float* dt_proj  = (const float*)d_in[2];
    const float* A_log    = (const float*)d_in[3];
    const float* B_proj   = (const float*)d_in[4];
    const float* C_proj   = (const float*)d_in[5];
    const float* Dvec     = (const float*)d_in[6];
    const float* out_proj = (const float*)d_in[7];
    const float* dt_bias  = (const float*)d_in[8];
    float* out = (float*)d_out;

    float* ws = (float*)d_ws;
    float* DT   = ws;                                    // 16384*16
    float* BM   = DT   + (size_t)M_ROWS*DSTATE;
    float* CM   = BM   + (size_t)M_ROWS*DSTATE;
    float* HEND = CM   + (size_t)M_ROWS*DSTATE;          // [b][chunk][d][s]
    float* PPRO = HEND + (size_t)BATCH*NCHUNK*DINNER*DSTATE;
    float* H0   = PPRO + (size_t)BATCH*NCHUNK*DINNER*DSTATE;
    u16*   Y2hi = (u16*)(H0 + (size_t)BATCH*NCHUNK*DINNER*DSTATE);
    u16*   Y2lo = Y2hi + (size_t)M_ROWS*DINNER;
    u16*   W1hi = Y2lo + (size_t)M_ROWS*DINNER;
    u16*   W1lo = W1hi + (size_t)NDIM*1024;
    u16*   W4hi = W1lo + (size_t)NDIM*1024;
    u16*   W4lo = W4hi + (size_t)DINNER*NDIM;
    u16*   Wphi = W4lo + (size_t)DINNER*NDIM;            // 32768 each
    u16*   Wplo = Wphi + (size_t)32768;
    u16*   Uhi  = Wplo + (size_t)32768;                  // 16384*512 each
    u16*   Ulo  = Uhi  + (size_t)M_ROWS*DINNER;
    u16*   Ghi  = Ulo  + (size_t)M_ROWS*DINNER;
    u16*   Glo  = Ghi  + (size_t)M_ROWS*DINNER;
    // Xhi/Xlo alias Y2hi/Y2lo: X consumed by K1 before scan_c writes Y2.
    u16*   Xhi  = Y2hi;
    u16*   Xlo  = Y2lo;

    prep_x<<<dim3(M_ROWS*NDIM/4/256), 256, 0, stream>>>(x, Xhi, Xlo);
    prep_w<1024,10><<<dim3(NDIM*1024/256), 256, 0, stream>>>(x_proj, W1hi, W1lo);
    prep_w<256,8><<<dim3(DINNER*NDIM/256), 256, 0, stream>>>(out_proj, W4hi, W4lo);
    prep_w_proj<<<dim3(128), 256, 0, stream>>>(dt_proj, B_proj, C_proj, Wphi, Wplo);

    mfma_gemm<1024, 256, true><<<dim3(8, M_ROWS/128), 256, 0, stream>>>(
        Xhi, Xlo, W1hi, W1lo, nullptr, Uhi, Ulo, Ghi, Glo);
    proj_mfma<<<dim3(M_ROWS/64), 256, 0, stream>>>(Uhi, Ulo, Wphi, Wplo,
                                                   dt_bias, DT, BM, CM);
    scan_phase_a<<<dim3(NCHUNK, DINNER/256, BATCH), 256, 0, stream>>>(
        DT, BM, Uhi, Ulo, A_log, HEND, PPRO);
    scan_phase_b<<<dim3(128), 256, 0, stream>>>(HEND, PPRO, H0);
    scan_phase_c<<<dim3(NCHUNK, DINNER/256, BATCH), 256, 0, stream>>>(
        DT, BM, CM, Uhi, Ulo, Ghi, Glo, A_log, Dvec, H0, Y2hi, Y2lo);
    mfma_gemm<256, 512, false><<<dim3(2, M_ROWS/128), 256, 0, stream>>>(
        Y2hi, Y2lo, W4hi, W4lo, out, nullptr, nullptr, nullptr, nullptr);
}

// Round 9
// 247.353 us; speedup vs baseline: 1.1853x; 1.1853x over previous
//
#include <hip/hip_runtime.h>
#include <math.h>

#define BATCH   4
#define SEQLEN  4096
#define NDIM    256
#define DINNER  512
#define DSTATE  16
#define M_ROWS  (BATCH*SEQLEN)   // 16384
#define CHUNK   64
#define NCHUNK  (SEQLEN/CHUNK)   // 64

typedef _Float16 half8 __attribute__((ext_vector_type(8)));
typedef _Float16 half4 __attribute__((ext_vector_type(4)));
typedef float floatx4 __attribute__((ext_vector_type(4)));

// ---------------------------------------------------------------------------
// prep_x: x (M_ROWS x 256 fp32) -> X fp16 row-major (single array; 2^-12 rel).
// ---------------------------------------------------------------------------
__global__ __launch_bounds__(256)
void prep_x(const float* __restrict__ X, _Float16* __restrict__ Xh) {
    const size_t t = (size_t)blockIdx.x * 256 + threadIdx.x;
    const float4 v = ((const float4*)X)[t];
    half4 h;
    h.x = (_Float16)v.x; h.y = (_Float16)v.y;
    h.z = (_Float16)v.z; h.w = (_Float16)v.w;
    ((half4*)Xh)[t] = h;
}

// ---------------------------------------------------------------------------
// prep_w: W (K x N fp32) -> packed hi/lo fp16 in B-fragment order:
// out[((kb*4+q)*N + n)*8 + j] = W[(kb*32+q*8+j)*N + n].
// hi = RN(w), lo = RN(w - hi): 2-product split recovers ~22 mantissa bits.
// ---------------------------------------------------------------------------
template<int N, int LOGN>
__global__ __launch_bounds__(256)
void prep_w(const float* __restrict__ W, _Float16* __restrict__ Whi,
            _Float16* __restrict__ Wlo) {
    const int t = blockIdx.x * 256 + threadIdx.x;
    const int j  = t & 7;
    const int n  = (t >> 3) & (N - 1);
    const int q  = (t >> (3 + LOGN)) & 3;
    const int kb = t >> (5 + LOGN);
    const int k  = kb * 32 + q * 8 + j;
    const float v = W[(size_t)k * N + n];
    const _Float16 hi = (_Float16)v;
    Whi[t] = hi;
    Wlo[t] = (_Float16)(v - (float)hi);
}

// ---------------------------------------------------------------------------
// prep_w_proj: pack [Wdt|Wb|Wc|zeros] (512 x 64 logical) into B-frag order.
// ---------------------------------------------------------------------------
__global__ __launch_bounds__(256)
void prep_w_proj(const float* __restrict__ Wdt, const float* __restrict__ Wb,
                 const float* __restrict__ Wc, _Float16* __restrict__ Whi,
                 _Float16* __restrict__ Wlo) {
    const int t = blockIdx.x * 256 + threadIdx.x;   // < 32768
    const int n  = (t >> 3) & 63;
    const int q  = (t >> 9) & 3;
    const int kb = t >> 11;
    const int k  = kb * 32 + q * 8 + (t & 7);
    float v;
    if      (n < 16) v = Wdt[(size_t)k * 16 + n];
    else if (n < 32) v = Wb [(size_t)k * 16 + (n - 16)];
    else if (n < 48) v = Wc [(size_t)k * 16 + (n - 32)];
    else             v = 0.f;
    const _Float16 hi = (_Float16)v;
    Whi[t] = hi;
    Wlo[t] = (_Float16)(v - (float)hi);
}

// ---------------------------------------------------------------------------
// 2-product fp16 MFMA GEMM, NO LDS: A single fp16 row-major (frag = one
// 16B short8 load), B packed hi/lo. acc = a*bh + a*bl (fp32 accumulate).
// No barriers in the K-loop. SILU=true: silu -> fp16 U (cols<512) / G (>=512).
// ---------------------------------------------------------------------------
template<int NT, int KT, bool SILU>
__global__ __launch_bounds__(256)
void mfma_gemm(const _Float16* __restrict__ Ah,
               const _Float16* __restrict__ Whi, const _Float16* __restrict__ Wlo,
               float* __restrict__ Ofp,
               _Float16* __restrict__ O1, _Float16* __restrict__ O2) {
    const int tid = threadIdx.x;
    const int lane = tid & 63;
    const int w  = tid >> 6;
    const int wm = w >> 1, wn = w & 1;
    const int n0 = blockIdx.x * 128;
    const int m0 = blockIdx.y * 128;
    const int l15 = lane & 15, q = lane >> 4;

    floatx4 acc[4][4];
    const floatx4 zero = {0.f, 0.f, 0.f, 0.f};
    #pragma unroll
    for (int i = 0; i < 4; i++)
        #pragma unroll
        for (int j = 0; j < 4; j++) acc[i][j] = zero;

    // per-lane A row base (row = m0 + wm*64 + mt*16 + l15, k = kb*32 + q*8)
    const _Float16* aBase = Ah + (size_t)(m0 + wm * 64 + l15) * KT + q * 8;

    for (int kb = 0; kb < KT / 32; kb++) {
        half8 bh[4], bl[4], a[4];
        #pragma unroll
        for (int mt = 0; mt < 4; mt++)
            a[mt] = *(const half8*)(aBase + (size_t)(mt * 16) * KT + kb * 32);
        #pragma unroll
        for (int nt = 0; nt < 4; nt++) {
            const size_t off =
                ((size_t)((kb * 4 + q) * NT) + n0 + wn * 64 + nt * 16 + l15) * 8;
            bh[nt] = *(const half8*)(Whi + off);
            bl[nt] = *(const half8*)(Wlo + off);
        }
        #pragma unroll
        for (int mt = 0; mt < 4; mt++)
            #pragma unroll
            for (int nt = 0; nt < 4; nt++) {
                acc[mt][nt] = __builtin_amdgcn_mfma_f32_16x16x32_f16(
                    a[mt], bh[nt], acc[mt][nt], 0, 0, 0);
                acc[mt][nt] = __builtin_amdgcn_mfma_f32_16x16x32_f16(
                    a[mt], bl[nt], acc[mt][nt], 0, 0, 0);
            }
    }
    // epilogue: D col=lane&15, row=quad*4+reg  [verified m89/m91; dtype-indep]
    #pragma unroll
    for (int mt = 0; mt < 4; mt++) {
        #pragma unroll
        for (int nt = 0; nt < 4; nt++) {
            const int col = n0 + wn * 64 + nt * 16 + l15;
            #pragma unroll
            for (int r = 0; r < 4; r++) {
                const int row = m0 + wm * 64 + mt * 16 + q * 4 + r;
                float v = acc[mt][nt][r];
                if (SILU) {
                    v = v / (1.f + __expf(-v));
                    if (col < DINNER) {
                        O1[(size_t)row * DINNER + col] = (_Float16)v;
                    } else {
                        O2[(size_t)row * DINNER + col - DINNER] = (_Float16)v;
                    }
                } else {
                    Ofp[(size_t)row * NT + col] = v;
                }
            }
        }
    }
}

// ---------------------------------------------------------------------------
// proj_mfma, NO LDS: U (fp16) @ Wp (512x64 packed hi/lo; 48 real cols) ->
// DT (softplus+bias) / BM / CM. 256 blocks x 64 rows, waves 2x2 of 32x32.
// ---------------------------------------------------------------------------
__global__ __launch_bounds__(256)
void proj_mfma(const _Float16* __restrict__ Uh,
               const _Float16* __restrict__ Whi, const _Float16* __restrict__ Wlo,
               const float* __restrict__ bias,
               float* __restrict__ DT, float* __restrict__ BM,
               float* __restrict__ CM) {
    const int tid = threadIdx.x;
    const int lane = tid & 63;
    const int w  = tid >> 6;
    const int wm = w >> 1, wn = w & 1;
    const int m0 = blockIdx.x * 64;
    const int l15 = lane & 15, q = lane >> 4;

    floatx4 acc[2][2];
    const floatx4 zero = {0.f, 0.f, 0.f, 0.f};
    #pragma unroll
    for (int i = 0; i < 2; i++)
        #pragma unroll
        for (int j = 0; j < 2; j++) acc[i][j] = zero;

    const _Float16* aBase = Uh + (size_t)(m0 + wm * 32 + l15) * DINNER + q * 8;

    for (int kb = 0; kb < DINNER / 32; kb++) {
        half8 bh[2], bl[2], a[2];
        #pragma unroll
        for (int mt = 0; mt < 2; mt++)
            a[mt] = *(const half8*)(aBase + (size_t)(mt * 16) * DINNER + kb * 32);
        #pragma unroll
        for (int nt = 0; nt < 2; nt++) {
            const size_t off =
                ((size_t)((kb * 4 + q) * 64) + wn * 32 + nt * 16 + l15) * 8;
            bh[nt] = *(const half8*)(Whi + off);
            bl[nt] = *(const half8*)(Wlo + off);
        }
        #pragma unroll
        for (int mt = 0; mt < 2; mt++)
            #pragma unroll
            for (int nt = 0; nt < 2; nt++) {
                acc[mt][nt] = __builtin_amdgcn_mfma_f32_16x16x32_f16(
                    a[mt], bh[nt], acc[mt][nt], 0, 0, 0);
                acc[mt][nt] = __builtin_amdgcn_mfma_f32_16x16x32_f16(
                    a[mt], bl[nt], acc[mt][nt], 0, 0, 0);
            }
    }
    #pragma unroll
    for (int mt = 0; mt < 2; mt++) {
        #pragma unroll
        for (int nt = 0; nt < 2; nt++) {
            const int col = wn * 32 + nt * 16 + l15;
            #pragma unroll
            for (int r = 0; r < 4; r++) {
                const int row = m0 + wm * 32 + mt * 16 + q * 4 + r;
                float v = acc[mt][nt][r];
                if (col < 16) {
                    float dv = v + bias[col];
                    dv = (dv > 20.f) ? dv : log1pf(__expf(dv));
                    DT[(size_t)row * 16 + col] = dv;
                } else if (col < 32) {
                    BM[(size_t)row * 16 + (col - 16)] = v;
                } else if (col < 48) {
                    CM[(size_t)row * 16 + (col - 32)] = v;
                }
            }
        }
    }
}

// ---------------------------------------------------------------------------
// K3a: chunked scan phase A. One thread per d; 16 states in registers.
// u read as fp16 (one load).
// ---------------------------------------------------------------------------
__global__ __launch_bounds__(256)
void scan_phase_a(const float* __restrict__ DT, const float* __restrict__ BM,
                  const _Float16* __restrict__ Uh,
                  const float* __restrict__ Alog,
                  float* __restrict__ HEND, float* __restrict__ PPROD) {
    __shared__ float s_dt[CHUNK][DSTATE];
    __shared__ float s_db[CHUNK][DSTATE];
    const int tid = threadIdx.x;
    const int chunk = blockIdx.x;
    const int dg = blockIdx.y;
    const int b  = blockIdx.z;
    const int d  = dg*256 + tid;
    const int l0 = chunk * CHUNK;
    {
        const float4 dtv = ((const float4*)(DT + (size_t)(b*SEQLEN + l0)*16))[tid];
        const float4 bmv = ((const float4*)(BM + (size_t)(b*SEQLEN + l0)*16))[tid];
        ((float4*)&s_dt[0][0])[tid] = dtv;
        float4 dbv;
        dbv.x = dtv.x*bmv.x; dbv.y = dtv.y*bmv.y;
        dbv.z = dtv.z*bmv.z; dbv.w = dtv.w*bmv.w;
        ((float4*)&s_db[0][0])[tid] = dbv;
    }
    __syncthreads();
    float A[DSTATE];
    #pragma unroll
    for (int qq = 0; qq < 4; qq++) {
        const float4 av = ((const float4*)(Alog + (size_t)d*16))[qq];
        A[4*qq+0] = -__expf(av.x); A[4*qq+1] = -__expf(av.y);
        A[4*qq+2] = -__expf(av.z); A[4*qq+3] = -__expf(av.w);
    }
    float h[DSTATE] = {};
    float P[DSTATE];
    #pragma unroll
    for (int s = 0; s < DSTATE; s++) P[s] = 1.f;
    const _Float16* uhp = Uh + ((size_t)(b*SEQLEN + l0))*DINNER + d;
    for (int l = 0; l < CHUNK; l++) {
        const float u = (float)uhp[(size_t)l*DINNER];
        #pragma unroll
        for (int s = 0; s < DSTATE; s++) {
            const float dA = __expf(s_dt[l][s] * A[s]);
            h[s] = dA*h[s] + s_db[l][s]*u;
            P[s] *= dA;
        }
    }
    float* he = HEND  + ((size_t)(b*NCHUNK + chunk)*DINNER + d)*16;
    float* pp = PPROD + ((size_t)(b*NCHUNK + chunk)*DINNER + d)*16;
    #pragma unroll
    for (int qq = 0; qq < 4; qq++) {
        float4 hv, pv;
        hv.x = h[4*qq+0]; hv.y = h[4*qq+1]; hv.z = h[4*qq+2]; hv.w = h[4*qq+3];
        pv.x = P[4*qq+0]; pv.y = P[4*qq+1]; pv.z = P[4*qq+2]; pv.w = P[4*qq+3];
        ((float4*)he)[qq] = hv;
        ((float4*)pp)[qq] = pv;
    }
}

// ---------------------------------------------------------------------------
// K3b: sequential chain over chunks. Thread per (b,d,s) = 32768.
// ---------------------------------------------------------------------------
__global__ __launch_bounds__(256)
void scan_phase_b(const float* __restrict__ HEND, const float* __restrict__ PPROD,
                  float* __restrict__ H0) {
    const int tid = threadIdx.x;
    const int s  = tid & 15;
    const int dl = tid >> 4;
    const int blk = blockIdx.x;
    const int b  = blk >> 5;
    const int dg = blk & 31;
    const int d  = dg*16 + dl;
    float h = 0.f;
    for (int c0 = 0; c0 < NCHUNK; c0 += 8) {
        float Pv[8], Hv[8];
        #pragma unroll
        for (int j = 0; j < 8; j++) {
            const size_t idx = ((size_t)(b*NCHUNK + c0 + j)*DINNER + d)*16 + s;
            Pv[j] = PPROD[idx];
            Hv[j] = HEND [idx];
        }
        #pragma unroll
        for (int j = 0; j < 8; j++) {
            H0[((size_t)(b*NCHUNK + c0 + j)*DINNER + d)*16 + s] = h;
            h = Pv[j]*h + Hv[j];
        }
    }
}

// ---------------------------------------------------------------------------
// K3c: rerun chunks from true initial state; u,g read as fp16; emit Y2 fp16.
// Fused skip (u*D) and gate (g).
// ---------------------------------------------------------------------------
__global__ __launch_bounds__(256)
void scan_phase_c(const float* __restrict__ DT, const float* __restrict__ BM,
                  const float* __restrict__ CM,
                  const _Float16* __restrict__ Uh, const _Float16* __restrict__ Gh,
                  const float* __restrict__ Alog,
                  const float* __restrict__ Dvec, const float* __restrict__ H0,
                  _Float16* __restrict__ Y2) {
    __shared__ float s_dt[CHUNK][DSTATE];
    __shared__ float s_db[CHUNK][DSTATE];
    __shared__ float s_c [CHUNK][DSTATE];
    const int tid = threadIdx.x;
    const int chunk = blockIdx.x;
    const int dg = blockIdx.y;
    const int b  = blockIdx.z;
    const int d  = dg*256 + tid;
    const int l0 = chunk * CHUNK;
    {
        const float4 dtv = ((const float4*)(DT + (size_t)(b*SEQLEN + l0)*16))[tid];
        const float4 bmv = ((const float4*)(BM + (size_t)(b*SEQLEN + l0)*16))[tid];
        const float4 cmv = ((const float4*)(CM + (size_t)(b*SEQLEN + l0)*16))[tid];
        ((float4*)&s_dt[0][0])[tid] = dtv;
        float4 dbv;
        dbv.x = dtv.x*bmv.x; dbv.y = dtv.y*bmv.y;
        dbv.z = dtv.z*bmv.z; dbv.w = dtv.w*bmv.w;
        ((float4*)&s_db[0][0])[tid] = dbv;
        ((float4*)&s_c [0][0])[tid] = cmv;
    }
    __syncthreads();
    float A[DSTATE];
    #pragma unroll
    for (int qq = 0; qq < 4; qq++) {
        const float4 av = ((const float4*)(Alog + (size_t)d*16))[qq];
        A[4*qq+0] = -__expf(av.x); A[4*qq+1] = -__expf(av.y);
        A[4*qq+2] = -__expf(av.z); A[4*qq+3] = -__expf(av.w);
    }
    float h[DSTATE];
    {
        const float* h0 = H0 + ((size_t)(b*NCHUNK + chunk)*DINNER + d)*16;
        #pragma unroll
        for (int qq = 0; qq < 4; qq++) {
            const float4 hv = ((const float4*)h0)[qq];
            h[4*qq+0] = hv.x; h[4*qq+1] = hv.y; h[4*qq+2] = hv.z; h[4*qq+3] = hv.w;
        }
    }
    const float Dd = Dvec[d];
    const size_t base = ((size_t)(b*SEQLEN + l0))*DINNER + d;
    const _Float16* uhp = Uh + base;
    const _Float16* ghp = Gh + base;
    _Float16* yp = Y2 + base;
    for (int l = 0; l < CHUNK; l++) {
        const float u = (float)uhp[(size_t)l*DINNER];
        const float g = (float)ghp[(size_t)l*DINNER];
        float y = 0.f;
        #pragma unroll
        for (int s = 0; s < DSTATE; s++) {
            const float dA = __expf(s_dt[l][s] * A[s]);
            h[s] = dA*h[s] + s_db[l][s]*u;
            y += h[s]*s_c[l][s];
        }
        yp[(size_t)l*DINNER] = (_Float16)((y + u*Dd) * g);
    }
}

// ---------------------------------------------------------------------------
extern "C" void kernel_launch(void* const* d_in, const int* in_sizes, int n_in,
                              void* d_out, int out_size, void* d_ws, size_t ws_size,
                              hipStream_t stream) {
    const float* x        = (const float*)d_in[0];
    const float* x_proj   = (const float*)d_in[1];
    const float* dt_proj  = (const float*)d_in[2];
    const float* A_log    = (const float*)d_in[3];
    const float* B_proj   = (const float*)d_in[4];
    const float* C_proj   = (const float*)d_in[5];
    const float* Dvec     = (const float*)d_in[6];
    const float* out_proj = (const float*)d_in[7];
    const float* dt_bias  = (const float*)d_in[8];
    float* out = (float*)d_out;

    float* ws = (float*)d_ws;
    float* DT   = ws;                                    // 16384*16
    float* BM   = DT   + (size_t)M_ROWS*DSTATE;
    float* CM   = BM   + (size_t)M_ROWS*DSTATE;
    float* HEND = CM   + (size_t)M_ROWS*DSTATE;          // [b][chunk][d][s]
    float* PPRO = HEND + (size_t)BATCH*NCHUNK*DINNER*DSTATE;
    float* H0   = PPRO + (size_t)BATCH*NCHUNK*DINNER*DSTATE;
    _Float16* Y2   = (_Float16*)(H0 + (size_t)BATCH*NCHUNK*DINNER*DSTATE);
    _Float16* W1hi = Y2   + (size_t)M_ROWS*DINNER;
    _Float16* W1lo = W1hi + (size_t)NDIM*1024;
    _Float16* W4hi = W1lo + (size_t)NDIM*1024;
    _Float16* W4lo = W4hi + (size_t)DINNER*NDIM;
    _Float16* Wphi = W4lo + (size_t)DINNER*NDIM;         // 32768 each
    _Float16* Wplo = Wphi + (size_t)32768;
    _Float16* Uh   = Wplo + (size_t)32768;               // 16384*512
    _Float16* Gh   = Uh   + (size_t)M_ROWS*DINNER;
    // Xh aliases Y2 (X fp16 = 8.4MB < Y2's 16.8MB): X consumed by K1
    // (dispatch 5) before scan_c (dispatch 9) writes Y2. Stream-ordered safe.
    _Float16* Xh   = Y2;

    prep_x<<<dim3(M_ROWS*NDIM/4/256), 256, 0, stream>>>(x, Xh);
    prep_w<1024,10><<<dim3(NDIM*1024/256), 256, 0, stream>>>(x_proj, W1hi, W1lo);
    prep_w<256,8><<<dim3(DINNER*NDIM/256), 256, 0, stream>>>(out_proj, W4hi, W4lo);
    prep_w_proj<<<dim3(128), 256, 0, stream>>>(dt_proj, B_proj, C_proj, Wphi, Wplo);

    mfma_gemm<1024, 256, true><<<dim3(8, M_ROWS/128), 256, 0, stream>>>(
        Xh, W1hi, W1lo, nullptr, Uh, Gh);
    proj_mfma<<<dim3(M_ROWS/64), 256, 0, stream>>>(Uh, Wphi, Wplo,
                                                   dt_bias, DT, BM, CM);
    scan_phase_a<<<dim3(NCHUNK, DINNER/256, BATCH), 256, 0, stream>>>(
        DT, BM, Uh, A_log, HEND, PPRO);
    scan_phase_b<<<dim3(128), 256, 0, stream>>>(HEND, PPRO, H0);
    scan_phase_c<<<dim3(NCHUNK, DINNER/256, BATCH), 256, 0, stream>>>(
        DT, BM, CM, Uh, Gh, A_log, Dvec, H0, Y2);
    mfma_gemm<256, 512, false><<<dim3(2, M_ROWS/128), 256, 0, stream>>>(
        Y2, W4hi, W4lo, out, nullptr, nullptr);
}

// Round 10
// 243.161 us; speedup vs baseline: 1.2058x; 1.0172x over previous
//
#include <hip/hip_runtime.h>
#include <math.h>

#define BATCH   4
#define SEQLEN  4096
#define NDIM    256
#define DINNER  512
#define DSTATE  16
#define M_ROWS  (BATCH*SEQLEN)   // 16384
#define CHUNK   64
#define NCHUNK  (SEQLEN/CHUNK)   // 64

typedef _Float16 half8 __attribute__((ext_vector_type(8)));
typedef _Float16 half4 __attribute__((ext_vector_type(4)));
typedef float floatx4 __attribute__((ext_vector_type(4)));

// ---------------------------------------------------------------------------
// prep_x: x (M_ROWS x 256 fp32) -> X fp16 row-major.
// ---------------------------------------------------------------------------
__global__ __launch_bounds__(256)
void prep_x(const float* __restrict__ X, _Float16* __restrict__ Xh) {
    const size_t t = (size_t)blockIdx.x * 256 + threadIdx.x;
    const float4 v = ((const float4*)X)[t];
    half4 h;
    h.x = (_Float16)v.x; h.y = (_Float16)v.y;
    h.z = (_Float16)v.z; h.w = (_Float16)v.w;
    ((half4*)Xh)[t] = h;
}

// ---------------------------------------------------------------------------
// prep_w: W (K x N fp32) -> fp16 (hi only) in B-fragment order:
// out[((kb*4+q)*N + n)*8 + j] = W[(kb*32+q*8+j)*N + n].
// ---------------------------------------------------------------------------
template<int N, int LOGN>
__global__ __launch_bounds__(256)
void prep_w(const float* __restrict__ W, _Float16* __restrict__ Wh) {
    const int t = blockIdx.x * 256 + threadIdx.x;
    const int j  = t & 7;
    const int n  = (t >> 3) & (N - 1);
    const int q  = (t >> (3 + LOGN)) & 3;
    const int kb = t >> (5 + LOGN);
    const int k  = kb * 32 + q * 8 + j;
    Wh[t] = (_Float16)W[(size_t)k * N + n];
}

// ---------------------------------------------------------------------------
// prep_w_proj: pack [Wdt|Wb|Wc|zeros] (512 x 64) into B-frag order, hi/lo
// (proj keeps 2-product: dt feeds exp chains — most error-sensitive).
// ---------------------------------------------------------------------------
__global__ __launch_bounds__(256)
void prep_w_proj(const float* __restrict__ Wdt, const float* __restrict__ Wb,
                 const float* __restrict__ Wc, _Float16* __restrict__ Whi,
                 _Float16* __restrict__ Wlo) {
    const int t = blockIdx.x * 256 + threadIdx.x;   // < 32768
    const int n  = (t >> 3) & 63;
    const int q  = (t >> 9) & 3;
    const int kb = t >> 11;
    const int k  = kb * 32 + q * 8 + (t & 7);
    float v;
    if      (n < 16) v = Wdt[(size_t)k * 16 + n];
    else if (n < 32) v = Wb [(size_t)k * 16 + (n - 16)];
    else if (n < 48) v = Wc [(size_t)k * 16 + (n - 32)];
    else             v = 0.f;
    const _Float16 hi = (_Float16)v;
    Whi[t] = hi;
    Wlo[t] = (_Float16)(v - (float)hi);
}

// ---------------------------------------------------------------------------
// K1: single-product fp16 MFMA GEMM, NO LDS. Block 128x128, waves 2x2 of
// 64x64. A frag = one 16B half8 global load; B from packed weights.
// silu epilogue -> fp16 U (cols<512) / G (cols>=512).
// ---------------------------------------------------------------------------
__global__ __launch_bounds__(256)
void mfma_gemm1(const _Float16* __restrict__ Ah, const _Float16* __restrict__ Wh,
                _Float16* __restrict__ O1, _Float16* __restrict__ O2) {
    const int KT = 256, NT = 1024;
    const int tid = threadIdx.x;
    const int lane = tid & 63;
    const int w  = tid >> 6;
    const int wm = w >> 1, wn = w & 1;
    const int n0 = blockIdx.x * 128;
    const int m0 = blockIdx.y * 128;
    const int l15 = lane & 15, q = lane >> 4;

    floatx4 acc[4][4];
    const floatx4 zero = {0.f, 0.f, 0.f, 0.f};
    #pragma unroll
    for (int i = 0; i < 4; i++)
        #pragma unroll
        for (int j = 0; j < 4; j++) acc[i][j] = zero;

    const _Float16* aBase = Ah + (size_t)(m0 + wm * 64 + l15) * KT + q * 8;

    for (int kb = 0; kb < KT / 32; kb++) {
        half8 b[4], a[4];
        #pragma unroll
        for (int mt = 0; mt < 4; mt++)
            a[mt] = *(const half8*)(aBase + (size_t)(mt * 16) * KT + kb * 32);
        #pragma unroll
        for (int nt = 0; nt < 4; nt++) {
            const size_t off =
                ((size_t)((kb * 4 + q) * NT) + n0 + wn * 64 + nt * 16 + l15) * 8;
            b[nt] = *(const half8*)(Wh + off);
        }
        #pragma unroll
        for (int mt = 0; mt < 4; mt++)
            #pragma unroll
            for (int nt = 0; nt < 4; nt++)
                acc[mt][nt] = __builtin_amdgcn_mfma_f32_16x16x32_f16(
                    a[mt], b[nt], acc[mt][nt], 0, 0, 0);
    }
    // epilogue: D col=lane&15, row=quad*4+reg  [verified m89/m91; dtype-indep]
    #pragma unroll
    for (int mt = 0; mt < 4; mt++) {
        #pragma unroll
        for (int nt = 0; nt < 4; nt++) {
            const int col = n0 + wn * 64 + nt * 16 + l15;
            #pragma unroll
            for (int r = 0; r < 4; r++) {
                const int row = m0 + wm * 64 + mt * 16 + q * 4 + r;
                float v = acc[mt][nt][r];
                v = v / (1.f + __expf(-v));
                if (col < DINNER) O1[(size_t)row * DINNER + col] = (_Float16)v;
                else              O2[(size_t)row * DINNER + col - DINNER] = (_Float16)v;
            }
        }
    }
}

// ---------------------------------------------------------------------------
// K4: single-product fp16 MFMA GEMM, NO LDS. Block 128x64 (grid 4x128 = 512
// blocks = 2/CU), waves 2x2 of 64x32. Out fp32.
// ---------------------------------------------------------------------------
__global__ __launch_bounds__(256)
void mfma_gemm4(const _Float16* __restrict__ Ah, const _Float16* __restrict__ Wh,
                float* __restrict__ Out) {
    const int KT = 512, NT = 256;
    const int tid = threadIdx.x;
    const int lane = tid & 63;
    const int w  = tid >> 6;
    const int wm = w >> 1, wn = w & 1;
    const int n0 = blockIdx.x * 64;
    const int m0 = blockIdx.y * 128;
    const int l15 = lane & 15, q = lane >> 4;

    floatx4 acc[4][2];
    const floatx4 zero = {0.f, 0.f, 0.f, 0.f};
    #pragma unroll
    for (int i = 0; i < 4; i++)
        #pragma unroll
        for (int j = 0; j < 2; j++) acc[i][j] = zero;

    const _Float16* aBase = Ah + (size_t)(m0 + wm * 64 + l15) * KT + q * 8;

    for (int kb = 0; kb < KT / 32; kb++) {
        half8 b[2], a[4];
        #pragma unroll
        for (int mt = 0; mt < 4; mt++)
            a[mt] = *(const half8*)(aBase + (size_t)(mt * 16) * KT + kb * 32);
        #pragma unroll
        for (int nt = 0; nt < 2; nt++) {
            const size_t off =
                ((size_t)((kb * 4 + q) * NT) + n0 + wn * 32 + nt * 16 + l15) * 8;
            b[nt] = *(const half8*)(Wh + off);
        }
        #pragma unroll
        for (int mt = 0; mt < 4; mt++)
            #pragma unroll
            for (int nt = 0; nt < 2; nt++)
                acc[mt][nt] = __builtin_amdgcn_mfma_f32_16x16x32_f16(
                    a[mt], b[nt], acc[mt][nt], 0, 0, 0);
    }
    #pragma unroll
    for (int mt = 0; mt < 4; mt++) {
        #pragma unroll
        for (int nt = 0; nt < 2; nt++) {
            const int col = n0 + wn * 32 + nt * 16 + l15;
            #pragma unroll
            for (int r = 0; r < 4; r++) {
                const int row = m0 + wm * 64 + mt * 16 + q * 4 + r;
                Out[(size_t)row * NT + col] = acc[mt][nt][r];
            }
        }
    }
}

// ---------------------------------------------------------------------------
// proj_mfma (2-product, NO LDS): U fp16 @ Wp (512x64 hi/lo; 48 real cols) ->
// DT (softplus+bias) / BM / CM. 256 blocks x 64 rows.
// ---------------------------------------------------------------------------
__global__ __launch_bounds__(256)
void proj_mfma(const _Float16* __restrict__ Uh,
               const _Float16* __restrict__ Whi, const _Float16* __restrict__ Wlo,
               const float* __restrict__ bias,
               float* __restrict__ DT, float* __restrict__ BM,
               float* __restrict__ CM) {
    const int tid = threadIdx.x;
    const int lane = tid & 63;
    const int w  = tid >> 6;
    const int wm = w >> 1, wn = w & 1;
    const int m0 = blockIdx.x * 64;
    const int l15 = lane & 15, q = lane >> 4;

    floatx4 acc[2][2];
    const floatx4 zero = {0.f, 0.f, 0.f, 0.f};
    #pragma unroll
    for (int i = 0; i < 2; i++)
        #pragma unroll
        for (int j = 0; j < 2; j++) acc[i][j] = zero;

    const _Float16* aBase = Uh + (size_t)(m0 + wm * 32 + l15) * DINNER + q * 8;

    for (int kb = 0; kb < DINNER / 32; kb++) {
        half8 bh[2], bl[2], a[2];
        #pragma unroll
        for (int mt = 0; mt < 2; mt++)
            a[mt] = *(const half8*)(aBase + (size_t)(mt * 16) * DINNER + kb * 32);
        #pragma unroll
        for (int nt = 0; nt < 2; nt++) {
            const size_t off =
                ((size_t)((kb * 4 + q) * 64) + wn * 32 + nt * 16 + l15) * 8;
            bh[nt] = *(const half8*)(Whi + off);
            bl[nt] = *(const half8*)(Wlo + off);
        }
        #pragma unroll
        for (int mt = 0; mt < 2; mt++)
            #pragma unroll
            for (int nt = 0; nt < 2; nt++) {
                acc[mt][nt] = __builtin_amdgcn_mfma_f32_16x16x32_f16(
                    a[mt], bh[nt], acc[mt][nt], 0, 0, 0);
                acc[mt][nt] = __builtin_amdgcn_mfma_f32_16x16x32_f16(
                    a[mt], bl[nt], acc[mt][nt], 0, 0, 0);
            }
    }
    #pragma unroll
    for (int mt = 0; mt < 2; mt++) {
        #pragma unroll
        for (int nt = 0; nt < 2; nt++) {
            const int col = wn * 32 + nt * 16 + l15;
            #pragma unroll
            for (int r = 0; r < 4; r++) {
                const int row = m0 + wm * 32 + mt * 16 + q * 4 + r;
                float v = acc[mt][nt][r];
                if (col < 16) {
                    float dv = v + bias[col];
                    dv = (dv > 20.f) ? dv : log1pf(__expf(dv));
                    DT[(size_t)row * 16 + col] = dv;
                } else if (col < 32) {
                    BM[(size_t)row * 16 + (col - 16)] = v;
                } else if (col < 48) {
                    CM[(size_t)row * 16 + (col - 32)] = v;
                }
            }
        }
    }
}

// ---------------------------------------------------------------------------
// K3a: chunked scan phase A. One thread per d; 16 states in registers.
// ---------------------------------------------------------------------------
__global__ __launch_bounds__(256)
void scan_phase_a(const float* __restrict__ DT, const float* __restrict__ BM,
                  const _Float16* __restrict__ Uh,
                  const float* __restrict__ Alog,
                  float* __restrict__ HEND, float* __restrict__ PPROD) {
    __shared__ float s_dt[CHUNK][DSTATE];
    __shared__ float s_db[CHUNK][DSTATE];
    const int tid = threadIdx.x;
    const int chunk = blockIdx.x;
    const int dg = blockIdx.y;
    const int b  = blockIdx.z;
    const int d  = dg*256 + tid;
    const int l0 = chunk * CHUNK;
    {
        const float4 dtv = ((const float4*)(DT + (size_t)(b*SEQLEN + l0)*16))[tid];
        const float4 bmv = ((const float4*)(BM + (size_t)(b*SEQLEN + l0)*16))[tid];
        ((float4*)&s_dt[0][0])[tid] = dtv;
        float4 dbv;
        dbv.x = dtv.x*bmv.x; dbv.y = dtv.y*bmv.y;
        dbv.z = dtv.z*bmv.z; dbv.w = dtv.w*bmv.w;
        ((float4*)&s_db[0][0])[tid] = dbv;
    }
    __syncthreads();
    float A[DSTATE];
    #pragma unroll
    for (int qq = 0; qq < 4; qq++) {
        const float4 av = ((const float4*)(Alog + (size_t)d*16))[qq];
        A[4*qq+0] = -__expf(av.x); A[4*qq+1] = -__expf(av.y);
        A[4*qq+2] = -__expf(av.z); A[4*qq+3] = -__expf(av.w);
    }
    float h[DSTATE] = {};
    float P[DSTATE];
    #pragma unroll
    for (int s = 0; s < DSTATE; s++) P[s] = 1.f;
    const _Float16* uhp = Uh + ((size_t)(b*SEQLEN + l0))*DINNER + d;
    for (int l = 0; l < CHUNK; l++) {
        const float u = (float)uhp[(size_t)l*DINNER];
        #pragma unroll
        for (int s = 0; s < DSTATE; s++) {
            const float dA = __expf(s_dt[l][s] * A[s]);
            h[s] = dA*h[s] + s_db[l][s]*u;
            P[s] *= dA;
        }
    }
    float* he = HEND  + ((size_t)(b*NCHUNK + chunk)*DINNER + d)*16;
    float* pp = PPROD + ((size_t)(b*NCHUNK + chunk)*DINNER + d)*16;
    #pragma unroll
    for (int qq = 0; qq < 4; qq++) {
        float4 hv, pv;
        hv.x = h[4*qq+0]; hv.y = h[4*qq+1]; hv.z = h[4*qq+2]; hv.w = h[4*qq+3];
        pv.x = P[4*qq+0]; pv.y = P[4*qq+1]; pv.z = P[4*qq+2]; pv.w = P[4*qq+3];
        ((float4*)he)[qq] = hv;
        ((float4*)pp)[qq] = pv;
    }
}

// ---------------------------------------------------------------------------
// K3b: sequential chain over chunks. Thread per (b,d,s) = 32768.
// ---------------------------------------------------------------------------
__global__ __launch_bounds__(256)
void scan_phase_b(const float* __restrict__ HEND, const float* __restrict__ PPROD,
                  float* __restrict__ H0) {
    const int tid = threadIdx.x;
    const int s  = tid & 15;
    const int dl = tid >> 4;
    const int blk = blockIdx.x;
    const int b  = blk >> 5;
    const int dg = blk & 31;
    const int d  = dg*16 + dl;
    float h = 0.f;
    for (int c0 = 0; c0 < NCHUNK; c0 += 8) {
        float Pv[8], Hv[8];
        #pragma unroll
        for (int j = 0; j < 8; j++) {
            const size_t idx = ((size_t)(b*NCHUNK + c0 + j)*DINNER + d)*16 + s;
            Pv[j] = PPROD[idx];
            Hv[j] = HEND [idx];
        }
        #pragma unroll
        for (int j = 0; j < 8; j++) {
            H0[((size_t)(b*NCHUNK + c0 + j)*DINNER + d)*16 + s] = h;
            h = Pv[j]*h + Hv[j];
        }
    }
}

// ---------------------------------------------------------------------------
// K3c: rerun chunks from true initial state; u,g fp16; emit Y2 fp16.
// Fused skip (u*D) and gate (g).
// ---------------------------------------------------------------------------
__global__ __launch_bounds__(256)
void scan_phase_c(const float* __restrict__ DT, const float* __restrict__ BM,
                  const float* __restrict__ CM,
                  const _Float16* __restrict__ Uh, const _Float16* __restrict__ Gh,
                  const float* __restrict__ Alog,
                  const float* __restrict__ Dvec, const float* __restrict__ H0,
                  _Float16* __restrict__ Y2) {
    __shared__ float s_dt[CHUNK][DSTATE];
    __shared__ float s_db[CHUNK][DSTATE];
    __shared__ float s_c [CHUNK][DSTATE];
    const int tid = threadIdx.x;
    const int chunk = blockIdx.x;
    const int dg = blockIdx.y;
    const int b  = blockIdx.z;
    const int d  = dg*256 + tid;
    const int l0 = chunk * CHUNK;
    {
        const float4 dtv = ((const float4*)(DT + (size_t)(b*SEQLEN + l0)*16))[tid];
        const float4 bmv = ((const float4*)(BM + (size_t)(b*SEQLEN + l0)*16))[tid];
        const float4 cmv = ((const float4*)(CM + (size_t)(b*SEQLEN + l0)*16))[tid];
        ((float4*)&s_dt[0][0])[tid] = dtv;
        float4 dbv;
        dbv.x = dtv.x*bmv.x; dbv.y = dtv.y*bmv.y;
        dbv.z = dtv.z*bmv.z; dbv.w = dtv.w*bmv.w;
        ((float4*)&s_db[0][0])[tid] = dbv;
        ((float4*)&s_c [0][0])[tid] = cmv;
    }
    __syncthreads();
    float A[DSTATE];
    #pragma unroll
    for (int qq = 0; qq < 4; qq++) {
        const float4 av = ((const float4*)(Alog + (size_t)d*16))[qq];
        A[4*qq+0] = -__expf(av.x); A[4*qq+1] = -__expf(av.y);
        A[4*qq+2] = -__expf(av.z); A[4*qq+3] = -__expf(av.w);
    }
    float h[DSTATE];
    {
        const float* h0 = H0 + ((size_t)(b*NCHUNK + chunk)*DINNER + d)*16;
        #pragma unroll
        for (int qq = 0; qq < 4; qq++) {
            const float4 hv = ((const float4*)h0)[qq];
            h[4*qq+0] = hv.x; h[4*qq+1] = hv.y; h[4*qq+2] = hv.z; h[4*qq+3] = hv.w;
        }
    }
    const float Dd = Dvec[d];
    const size_t base = ((size_t)(b*SEQLEN + l0))*DINNER + d;
    const _Float16* uhp = Uh + base;
    const _Float16* ghp = Gh + base;
    _Float16* yp = Y2 + base;
    for (int l = 0; l < CHUNK; l++) {
        const float u = (float)uhp[(size_t)l*DINNER];
        const float g = (float)ghp[(size_t)l*DINNER];
        float y = 0.f;
        #pragma unroll
        for (int s = 0; s < DSTATE; s++) {
            const float dA = __expf(s_dt[l][s] * A[s]);
            h[s] = dA*h[s] + s_db[l][s]*u;
            y += h[s]*s_c[l][s];
        }
        yp[(size_t)l*DINNER] = (_Float16)((y + u*Dd) * g);
    }
}

// ---------------------------------------------------------------------------
extern "C" void kernel_launch(void* const* d_in, const int* in_sizes, int n_in,
                              void* d_out, int out_size, void* d_ws, size_t ws_size,
                              hipStream_t stream) {
    const float* x        = (const float*)d_in[0];
    const float* x_proj   = (const float*)d_in[1];
    const float* dt_proj  = (const float*)d_in[2];
    const float* A_log    = (const float*)d_in[3];
    const float* B_proj   = (const float*)d_in[4];
    const float* C_proj   = (const float*)d_in[5];
    const float* Dvec     = (const float*)d_in[6];
    const float* out_proj = (const float*)d_in[7];
    const float* dt_bias  = (const float*)d_in[8];
    float* out = (float*)d_out;

    float* ws = (float*)d_ws;
    float* DT   = ws;                                    // 16384*16
    float* BM   = DT   + (size_t)M_ROWS*DSTATE;
    float* CM   = BM   + (size_t)M_ROWS*DSTATE;
    float* HEND = CM   + (size_t)M_ROWS*DSTATE;          // [b][chunk][d][s]
    float* PPRO = HEND + (size_t)BATCH*NCHUNK*DINNER*DSTATE;
    float* H0   = PPRO + (size_t)BATCH*NCHUNK*DINNER*DSTATE;
    _Float16* Y2   = (_Float16*)(H0 + (size_t)BATCH*NCHUNK*DINNER*DSTATE);
    _Float16* W1h  = Y2   + (size_t)M_ROWS*DINNER;
    _Float16* W4h  = W1h  + (size_t)NDIM*1024;
    _Float16* Wphi = W4h  + (size_t)DINNER*NDIM;         // 32768 each
    _Float16* Wplo = Wphi + (size_t)32768;
    _Float16* Uh   = Wplo + (size_t)32768;               // 16384*512
    _Float16* Gh   = Uh   + (size_t)M_ROWS*DINNER;
    // Xh aliases Y2: X consumed by K1 before scan_c writes Y2 (stream order).
    _Float16* Xh   = Y2;

    prep_x<<<dim3(M_ROWS*NDIM/4/256), 256, 0, stream>>>(x, Xh);
    prep_w<1024,10><<<dim3(NDIM*1024/256), 256, 0, stream>>>(x_proj, W1h);
    prep_w<256,8><<<dim3(DINNER*NDIM/256), 256, 0, stream>>>(out_proj, W4h);
    prep_w_proj<<<dim3(128), 256, 0, stream>>>(dt_proj, B_proj, C_proj, Wphi, Wplo);

    mfma_gemm1<<<dim3(8, M_ROWS/128), 256, 0, stream>>>(Xh, W1h, Uh, Gh);
    proj_mfma<<<dim3(M_ROWS/64), 256, 0, stream>>>(Uh, Wphi, Wplo,
                                                   dt_bias, DT, BM, CM);
    scan_phase_a<<<dim3(NCHUNK, DINNER/256, BATCH), 256, 0, stream>>>(
        DT, BM, Uh, A_log, HEND, PPRO);
    scan_phase_b<<<dim3(128), 256, 0, stream>>>(HEND, PPRO, H0);
    scan_phase_c<<<dim3(NCHUNK, DINNER/256, BATCH), 256, 0, stream>>>(
        DT, BM, CM, Uh, Gh, A_log, Dvec, H0, Y2);
    mfma_gemm4<<<dim3(4, M_ROWS/128), 256, 0, stream>>>(Y2, W4h, out);
}

// Round 11
// 227.418 us; speedup vs baseline: 1.2892x; 1.0692x over previous
//
#include <hip/hip_runtime.h>
#include <math.h>

#define BATCH   4
#define SEQLEN  4096
#define NDIM    256
#define DINNER  512
#define DSTATE  16
#define M_ROWS  (BATCH*SEQLEN)   // 16384
#define CHUNK   32
#define NCHUNK  (SEQLEN/CHUNK)   // 128

typedef _Float16 half8 __attribute__((ext_vector_type(8)));
typedef _Float16 half4 __attribute__((ext_vector_type(4)));
typedef float floatx4 __attribute__((ext_vector_type(4)));

// ---------------------------------------------------------------------------
// prep_x: x (M_ROWS x 256 fp32) -> X fp16 row-major.
// ---------------------------------------------------------------------------
__global__ __launch_bounds__(256)
void prep_x(const float* __restrict__ X, _Float16* __restrict__ Xh) {
    const size_t t = (size_t)blockIdx.x * 256 + threadIdx.x;
    const float4 v = ((const float4*)X)[t];
    half4 h;
    h.x = (_Float16)v.x; h.y = (_Float16)v.y;
    h.z = (_Float16)v.z; h.w = (_Float16)v.w;
    ((half4*)Xh)[t] = h;
}

// ---------------------------------------------------------------------------
// prep_w: W (K x N fp32) -> fp16 in B-fragment order:
// out[((kb*4+q)*N + n)*8 + j] = W[(kb*32+q*8+j)*N + n].
// ---------------------------------------------------------------------------
template<int N, int LOGN>
__global__ __launch_bounds__(256)
void prep_w(const float* __restrict__ W, _Float16* __restrict__ Wh) {
    const int t = blockIdx.x * 256 + threadIdx.x;
    const int j  = t & 7;
    const int n  = (t >> 3) & (N - 1);
    const int q  = (t >> (3 + LOGN)) & 3;
    const int kb = t >> (5 + LOGN);
    const int k  = kb * 32 + q * 8 + j;
    Wh[t] = (_Float16)W[(size_t)k * N + n];
}

// ---------------------------------------------------------------------------
// prep_w_proj: pack [Wdt|Wb|Wc|zeros] (512 x 64) into B-frag order, hi/lo
// (proj keeps 2-product: dt feeds exp chains — most error-sensitive).
// ---------------------------------------------------------------------------
__global__ __launch_bounds__(256)
void prep_w_proj(const float* __restrict__ Wdt, const float* __restrict__ Wb,
                 const float* __restrict__ Wc, _Float16* __restrict__ Whi,
                 _Float16* __restrict__ Wlo) {
    const int t = blockIdx.x * 256 + threadIdx.x;   // < 32768
    const int n  = (t >> 3) & 63;
    const int q  = (t >> 9) & 3;
    const int kb = t >> 11;
    const int k  = kb * 32 + q * 8 + (t & 7);
    float v;
    if      (n < 16) v = Wdt[(size_t)k * 16 + n];
    else if (n < 32) v = Wb [(size_t)k * 16 + (n - 16)];
    else if (n < 48) v = Wc [(size_t)k * 16 + (n - 32)];
    else             v = 0.f;
    const _Float16 hi = (_Float16)v;
    Whi[t] = hi;
    Wlo[t] = (_Float16)(v - (float)hi);
}

// ---------------------------------------------------------------------------
// K1: single-product fp16 MFMA GEMM, NO LDS. Block 128x128, waves 2x2 of
// 64x64. silu epilogue -> fp16 U (cols<512) / G (cols>=512).
// ---------------------------------------------------------------------------
__global__ __launch_bounds__(256)
void mfma_gemm1(const _Float16* __restrict__ Ah, const _Float16* __restrict__ Wh,
                _Float16* __restrict__ O1, _Float16* __restrict__ O2) {
    const int KT = 256, NT = 1024;
    const int tid = threadIdx.x;
    const int lane = tid & 63;
    const int w  = tid >> 6;
    const int wm = w >> 1, wn = w & 1;
    const int n0 = blockIdx.x * 128;
    const int m0 = blockIdx.y * 128;
    const int l15 = lane & 15, q = lane >> 4;

    floatx4 acc[4][4];
    const floatx4 zero = {0.f, 0.f, 0.f, 0.f};
    #pragma unroll
    for (int i = 0; i < 4; i++)
        #pragma unroll
        for (int j = 0; j < 4; j++) acc[i][j] = zero;

    const _Float16* aBase = Ah + (size_t)(m0 + wm * 64 + l15) * KT + q * 8;

    for (int kb = 0; kb < KT / 32; kb++) {
        half8 b[4], a[4];
        #pragma unroll
        for (int mt = 0; mt < 4; mt++)
            a[mt] = *(const half8*)(aBase + (size_t)(mt * 16) * KT + kb * 32);
        #pragma unroll
        for (int nt = 0; nt < 4; nt++) {
            const size_t off =
                ((size_t)((kb * 4 + q) * NT) + n0 + wn * 64 + nt * 16 + l15) * 8;
            b[nt] = *(const half8*)(Wh + off);
        }
        #pragma unroll
        for (int mt = 0; mt < 4; mt++)
            #pragma unroll
            for (int nt = 0; nt < 4; nt++)
                acc[mt][nt] = __builtin_amdgcn_mfma_f32_16x16x32_f16(
                    a[mt], b[nt], acc[mt][nt], 0, 0, 0);
    }
    // epilogue: D col=lane&15, row=quad*4+reg  [verified m89/m91; dtype-indep]
    #pragma unroll
    for (int mt = 0; mt < 4; mt++) {
        #pragma unroll
        for (int nt = 0; nt < 4; nt++) {
            const int col = n0 + wn * 64 + nt * 16 + l15;
            #pragma unroll
            for (int r = 0; r < 4; r++) {
                const int row = m0 + wm * 64 + mt * 16 + q * 4 + r;
                float v = acc[mt][nt][r];
                v = v / (1.f + __expf(-v));
                if (col < DINNER) O1[(size_t)row * DINNER + col] = (_Float16)v;
                else              O2[(size_t)row * DINNER + col - DINNER] = (_Float16)v;
            }
        }
    }
}

// ---------------------------------------------------------------------------
// K4: single-product fp16 MFMA GEMM, NO LDS. Block 128x64 (512 blocks),
// waves 2x2 of 64x32. Out fp32.
// ---------------------------------------------------------------------------
__global__ __launch_bounds__(256)
void mfma_gemm4(const _Float16* __restrict__ Ah, const _Float16* __restrict__ Wh,
                float* __restrict__ Out) {
    const int KT = 512, NT = 256;
    const int tid = threadIdx.x;
    const int lane = tid & 63;
    const int w  = tid >> 6;
    const int wm = w >> 1, wn = w & 1;
    const int n0 = blockIdx.x * 64;
    const int m0 = blockIdx.y * 128;
    const int l15 = lane & 15, q = lane >> 4;

    floatx4 acc[4][2];
    const floatx4 zero = {0.f, 0.f, 0.f, 0.f};
    #pragma unroll
    for (int i = 0; i < 4; i++)
        #pragma unroll
        for (int j = 0; j < 2; j++) acc[i][j] = zero;

    const _Float16* aBase = Ah + (size_t)(m0 + wm * 64 + l15) * KT + q * 8;

    for (int kb = 0; kb < KT / 32; kb++) {
        half8 b[2], a[4];
        #pragma unroll
        for (int mt = 0; mt < 4; mt++)
            a[mt] = *(const half8*)(aBase + (size_t)(mt * 16) * KT + kb * 32);
        #pragma unroll
        for (int nt = 0; nt < 2; nt++) {
            const size_t off =
                ((size_t)((kb * 4 + q) * NT) + n0 + wn * 32 + nt * 16 + l15) * 8;
            b[nt] = *(const half8*)(Wh + off);
        }
        #pragma unroll
        for (int mt = 0; mt < 4; mt++)
            #pragma unroll
            for (int nt = 0; nt < 2; nt++)
                acc[mt][nt] = __builtin_amdgcn_mfma_f32_16x16x32_f16(
                    a[mt], b[nt], acc[mt][nt], 0, 0, 0);
    }
    #pragma unroll
    for (int mt = 0; mt < 4; mt++) {
        #pragma unroll
        for (int nt = 0; nt < 2; nt++) {
            const int col = n0 + wn * 32 + nt * 16 + l15;
            #pragma unroll
            for (int r = 0; r < 4; r++) {
                const int row = m0 + wm * 64 + mt * 16 + q * 4 + r;
                Out[(size_t)row * NT + col] = acc[mt][nt][r];
            }
        }
    }
}

// ---------------------------------------------------------------------------
// proj_mfma (2-product, NO LDS): U fp16 @ Wp (512x64 hi/lo; 48 real cols) ->
// DT (softplus+bias) / BM / CM. 256 blocks x 64 rows.
// ---------------------------------------------------------------------------
__global__ __launch_bounds__(256)
void proj_mfma(const _Float16* __restrict__ Uh,
               const _Float16* __restrict__ Whi, const _Float16* __restrict__ Wlo,
               const float* __restrict__ bias,
               float* __restrict__ DT, float* __restrict__ BM,
               float* __restrict__ CM) {
    const int tid = threadIdx.x;
    const int lane = tid & 63;
    const int w  = tid >> 6;
    const int wm = w >> 1, wn = w & 1;
    const int m0 = blockIdx.x * 64;
    const int l15 = lane & 15, q = lane >> 4;

    floatx4 acc[2][2];
    const floatx4 zero = {0.f, 0.f, 0.f, 0.f};
    #pragma unroll
    for (int i = 0; i < 2; i++)
        #pragma unroll
        for (int j = 0; j < 2; j++) acc[i][j] = zero;

    const _Float16* aBase = Uh + (size_t)(m0 + wm * 32 + l15) * DINNER + q * 8;

    for (int kb = 0; kb < DINNER / 32; kb++) {
        half8 bh[2], bl[2], a[2];
        #pragma unroll
        for (int mt = 0; mt < 2; mt++)
            a[mt] = *(const half8*)(aBase + (size_t)(mt * 16) * DINNER + kb * 32);
        #pragma unroll
        for (int nt = 0; nt < 2; nt++) {
            const size_t off =
                ((size_t)((kb * 4 + q) * 64) + wn * 32 + nt * 16 + l15) * 8;
            bh[nt] = *(const half8*)(Whi + off);
            bl[nt] = *(const half8*)(Wlo + off);
        }
        #pragma unroll
        for (int mt = 0; mt < 2; mt++)
            #pragma unroll
            for (int nt = 0; nt < 2; nt++) {
                acc[mt][nt] = __builtin_amdgcn_mfma_f32_16x16x32_f16(
                    a[mt], bh[nt], acc[mt][nt], 0, 0, 0);
                acc[mt][nt] = __builtin_amdgcn_mfma_f32_16x16x32_f16(
                    a[mt], bl[nt], acc[mt][nt], 0, 0, 0);
            }
    }
    #pragma unroll
    for (int mt = 0; mt < 2; mt++) {
        #pragma unroll
        for (int nt = 0; nt < 2; nt++) {
            const int col = wn * 32 + nt * 16 + l15;
            #pragma unroll
            for (int r = 0; r < 4; r++) {
                const int row = m0 + wm * 32 + mt * 16 + q * 4 + r;
                float v = acc[mt][nt][r];
                if (col < 16) {
                    float dv = v + bias[col];
                    dv = (dv > 20.f) ? dv : log1pf(__expf(dv));
                    DT[(size_t)row * 16 + col] = dv;
                } else if (col < 32) {
                    BM[(size_t)row * 16 + (col - 16)] = v;
                } else if (col < 48) {
                    CM[(size_t)row * 16 + (col - 32)] = v;
                }
            }
        }
    }
}

// ---------------------------------------------------------------------------
// K3a: chunked scan phase A (CHUNK=32, 1024 blocks = 4/CU). One thread per d;
// states in floatx4[4]; LDS read as b128 (12x fewer issue slots than b32).
// ---------------------------------------------------------------------------
__global__ __launch_bounds__(256)
void scan_phase_a(const float* __restrict__ DT, const float* __restrict__ BM,
                  const _Float16* __restrict__ Uh,
                  const float* __restrict__ Alog,
                  float* __restrict__ HEND, float* __restrict__ PPROD) {
    __shared__ floatx4 sdt4[CHUNK * 4];   // 2 KB
    __shared__ floatx4 sdb4[CHUNK * 4];   // dt*B
    const int tid = threadIdx.x;
    const int chunk = blockIdx.x;
    const int dg = blockIdx.y;
    const int b  = blockIdx.z;
    const int d  = dg*256 + tid;
    const int l0 = chunk * CHUNK;
    if (tid < CHUNK * 4) {
        const floatx4 dtv = ((const floatx4*)(DT + (size_t)(b*SEQLEN + l0)*16))[tid];
        const floatx4 bmv = ((const floatx4*)(BM + (size_t)(b*SEQLEN + l0)*16))[tid];
        sdt4[tid] = dtv;
        sdb4[tid] = dtv * bmv;
    }
    __syncthreads();
    floatx4 A4[4];
    #pragma unroll
    for (int qq = 0; qq < 4; qq++) {
        const floatx4 av = ((const floatx4*)(Alog + (size_t)d*16))[qq];
        A4[qq].x = -__expf(av.x); A4[qq].y = -__expf(av.y);
        A4[qq].z = -__expf(av.z); A4[qq].w = -__expf(av.w);
    }
    floatx4 h4[4], P4[4];
    #pragma unroll
    for (int qq = 0; qq < 4; qq++) {
        h4[qq] = (floatx4){0.f, 0.f, 0.f, 0.f};
        P4[qq] = (floatx4){1.f, 1.f, 1.f, 1.f};
    }
    const _Float16* uhp = Uh + ((size_t)(b*SEQLEN + l0))*DINNER + d;
    #pragma unroll 4
    for (int l = 0; l < CHUNK; l++) {
        const float u = (float)uhp[(size_t)l*DINNER];
        #pragma unroll
        for (int qq = 0; qq < 4; qq++) {
            const floatx4 dtv = sdt4[l*4 + qq];
            const floatx4 dbv = sdb4[l*4 + qq];
            floatx4 dA;
            dA.x = __expf(dtv.x * A4[qq].x);
            dA.y = __expf(dtv.y * A4[qq].y);
            dA.z = __expf(dtv.z * A4[qq].z);
            dA.w = __expf(dtv.w * A4[qq].w);
            h4[qq] = dA * h4[qq] + dbv * u;
            P4[qq] *= dA;
        }
    }
    floatx4* he = (floatx4*)(HEND  + ((size_t)(b*NCHUNK + chunk)*DINNER + d)*16);
    floatx4* pp = (floatx4*)(PPROD + ((size_t)(b*NCHUNK + chunk)*DINNER + d)*16);
    #pragma unroll
    for (int qq = 0; qq < 4; qq++) {
        he[qq] = h4[qq];
        pp[qq] = P4[qq];
    }
}

// ---------------------------------------------------------------------------
// K3b: sequential chain over chunks (now 128). Thread per (b,d,s) = 32768.
// ---------------------------------------------------------------------------
__global__ __launch_bounds__(256)
void scan_phase_b(const float* __restrict__ HEND, const float* __restrict__ PPROD,
                  float* __restrict__ H0) {
    const int tid = threadIdx.x;
    const int s  = tid & 15;
    const int dl = tid >> 4;
    const int blk = blockIdx.x;
    const int b  = blk >> 5;
    const int dg = blk & 31;
    const int d  = dg*16 + dl;
    float h = 0.f;
    for (int c0 = 0; c0 < NCHUNK; c0 += 8) {
        float Pv[8], Hv[8];
        #pragma unroll
        for (int j = 0; j < 8; j++) {
            const size_t idx = ((size_t)(b*NCHUNK + c0 + j)*DINNER + d)*16 + s;
            Pv[j] = PPROD[idx];
            Hv[j] = HEND [idx];
        }
        #pragma unroll
        for (int j = 0; j < 8; j++) {
            H0[((size_t)(b*NCHUNK + c0 + j)*DINNER + d)*16 + s] = h;
            h = Pv[j]*h + Hv[j];
        }
    }
}

// ---------------------------------------------------------------------------
// K3c: rerun chunks from true initial state (CHUNK=32, 1024 blocks).
// floatx4 states, b128 LDS reads, serial y accumulator; emit Y2 fp16 fused
// with skip (u*D) and gate (g).
// ---------------------------------------------------------------------------
__global__ __launch_bounds__(256)
void scan_phase_c(const float* __restrict__ DT, const float* __restrict__ BM,
                  const float* __restrict__ CM,
                  const _Float16* __restrict__ Uh, const _Float16* __restrict__ Gh,
                  const float* __restrict__ Alog,
                  const float* __restrict__ Dvec, const float* __restrict__ H0,
                  _Float16* __restrict__ Y2) {
    __shared__ floatx4 sdt4[CHUNK * 4];
    __shared__ floatx4 sdb4[CHUNK * 4];
    __shared__ floatx4 sc4 [CHUNK * 4];
    const int tid = threadIdx.x;
    const int chunk = blockIdx.x;
    const int dg = blockIdx.y;
    const int b  = blockIdx.z;
    const int d  = dg*256 + tid;
    const int l0 = chunk * CHUNK;
    if (tid < CHUNK * 4) {
        const floatx4 dtv = ((const floatx4*)(DT + (size_t)(b*SEQLEN + l0)*16))[tid];
        const floatx4 bmv = ((const floatx4*)(BM + (size_t)(b*SEQLEN + l0)*16))[tid];
        sdt4[tid] = dtv;
        sdb4[tid] = dtv * bmv;
    } else {
        const int t2 = tid - CHUNK * 4;
        sc4[t2] = ((const floatx4*)(CM + (size_t)(b*SEQLEN + l0)*16))[t2];
    }
    __syncthreads();
    floatx4 A4[4];
    #pragma unroll
    for (int qq = 0; qq < 4; qq++) {
        const floatx4 av = ((const floatx4*)(Alog + (size_t)d*16))[qq];
        A4[qq].x = -__expf(av.x); A4[qq].y = -__expf(av.y);
        A4[qq].z = -__expf(av.z); A4[qq].w = -__expf(av.w);
    }
    floatx4 h4[4];
    {
        const floatx4* h0 = (const floatx4*)(H0 +
            ((size_t)(b*NCHUNK + chunk)*DINNER + d)*16);
        #pragma unroll
        for (int qq = 0; qq < 4; qq++) h4[qq] = h0[qq];
    }
    const float Dd = Dvec[d];
    const size_t base = ((size_t)(b*SEQLEN + l0))*DINNER + d;
    const _Float16* uhp = Uh + base;
    const _Float16* ghp = Gh + base;
    _Float16* yp = Y2 + base;
    #pragma unroll 4
    for (int l = 0; l < CHUNK; l++) {
        const float u = (float)uhp[(size_t)l*DINNER];
        const float g = (float)ghp[(size_t)l*DINNER];
        floatx4 y4 = {0.f, 0.f, 0.f, 0.f};
        #pragma unroll
        for (int qq = 0; qq < 4; qq++) {
            const floatx4 dtv = sdt4[l*4 + qq];
            const floatx4 dbv = sdb4[l*4 + qq];
            const floatx4 cv  = sc4 [l*4 + qq];
            floatx4 dA;
            dA.x = __expf(dtv.x * A4[qq].x);
            dA.y = __expf(dtv.y * A4[qq].y);
            dA.z = __expf(dtv.z * A4[qq].z);
            dA.w = __expf(dtv.w * A4[qq].w);
            h4[qq] = dA * h4[qq] + dbv * u;
            y4 += h4[qq] * cv;
        }
        const float y = y4.x + y4.y + y4.z + y4.w;
        yp[(size_t)l*DINNER] = (_Float16)((y + u*Dd) * g);
    }
}

// ---------------------------------------------------------------------------
extern "C" void kernel_launch(void* const* d_in, const int* in_sizes, int n_in,
                              void* d_out, int out_size, void* d_ws, size_t ws_size,
                              hipStream_t stream) {
    const float* x        = (const float*)d_in[0];
    const float* x_proj   = (const float*)d_in[1];
    const float* dt_proj  = (const float*)d_in[2];
    const float* A_log    = (const float*)d_in[3];
    const float* B_proj   = (const float*)d_in[4];
    const float* C_proj   = (const float*)d_in[5];
    const float* Dvec     = (const float*)d_in[6];
    const float* out_proj = (const float*)d_in[7];
    const float* dt_bias  = (const float*)d_in[8];
    float* out = (float*)d_out;

    float* ws = (float*)d_ws;
    float* DT   = ws;                                    // 16384*16
    float* BM   = DT   + (size_t)M_ROWS*DSTATE;
    float* CM   = BM   + (size_t)M_ROWS*DSTATE;
    float* HEND = CM   + (size_t)M_ROWS*DSTATE;          // [b][chunk][d][s]
    float* PPRO = HEND + (size_t)BATCH*NCHUNK*DINNER*DSTATE;
    float* H0   = PPRO + (size_t)BATCH*NCHUNK*DINNER*DSTATE;
    _Float16* Y2   = (_Float16*)(H0 + (size_t)BATCH*NCHUNK*DINNER*DSTATE);
    _Float16* W1h  = Y2   + (size_t)M_ROWS*DINNER;
    _Float16* W4h  = W1h  + (size_t)NDIM*1024;
    _Float16* Wphi = W4h  + (size_t)DINNER*NDIM;         // 32768 each
    _Float16* Wplo = Wphi + (size_t)32768;
    _Float16* Uh   = Wplo + (size_t)32768;               // 16384*512
    _Float16* Gh   = Uh   + (size_t)M_ROWS*DINNER;
    // Xh aliases Y2: X consumed by K1 before scan_c writes Y2 (stream order).
    _Float16* Xh   = Y2;

    prep_x<<<dim3(M_ROWS*NDIM/4/256), 256, 0, stream>>>(x, Xh);
    prep_w<1024,10><<<dim3(NDIM*1024/256), 256, 0, stream>>>(x_proj, W1h);
    prep_w<256,8><<<dim3(DINNER*NDIM/256), 256, 0, stream>>>(out_proj, W4h);
    prep_w_proj<<<dim3(128), 256, 0, stream>>>(dt_proj, B_proj, C_proj, Wphi, Wplo);

    mfma_gemm1<<<dim3(8, M_ROWS/128), 256, 0, stream>>>(Xh, W1h, Uh, Gh);
    proj_mfma<<<dim3(M_ROWS/64), 256, 0, stream>>>(Uh, Wphi, Wplo,
                                                   dt_bias, DT, BM, CM);
    scan_phase_a<<<dim3(NCHUNK, DINNER/256, BATCH), 256, 0, stream>>>(
        DT, BM, Uh, A_log, HEND, PPRO);
    scan_phase_b<<<dim3(128), 256, 0, stream>>>(HEND, PPRO, H0);
    scan_phase_c<<<dim3(NCHUNK, DINNER/256, BATCH), 256, 0, stream>>>(
        DT, BM, CM, Uh, Gh, A_log, Dvec, H0, Y2);
    mfma_gemm4<<<dim3(4, M_ROWS/128), 256, 0, stream>>>(Y2, W4h, out);
}

// Round 12
// 221.659 us; speedup vs baseline: 1.3227x; 1.0260x over previous
//
#include <hip/hip_runtime.h>
#include <math.h>

#define BATCH   4
#define SEQLEN  4096
#define NDIM    256
#define DINNER  512
#define DSTATE  16
#define M_ROWS  (BATCH*SEQLEN)   // 16384
#define CHUNK   32
#define NCHUNK  (SEQLEN/CHUNK)   // 128

typedef _Float16 half8 __attribute__((ext_vector_type(8)));
typedef _Float16 half4 __attribute__((ext_vector_type(4)));
typedef float floatx4 __attribute__((ext_vector_type(4)));

// ---------------------------------------------------------------------------
// prep_all: fused conversion/packing (one dispatch instead of four).
// blocks [0,4096): x -> Xh fp16 row-major
// blocks [4096,5120): x_proj -> W1h B-frag order
// blocks [5120,5632): out_proj -> W4h B-frag order
// blocks [5632,5760): [Wdt|Wb|Wc|0] -> Wphi/Wplo B-frag order (hi/lo)
// ---------------------------------------------------------------------------
__global__ __launch_bounds__(256)
void prep_all(const float* __restrict__ X, const float* __restrict__ Wx,
              const float* __restrict__ Wo, const float* __restrict__ Wdt,
              const float* __restrict__ Wb, const float* __restrict__ Wc,
              _Float16* __restrict__ Xh, _Float16* __restrict__ W1h,
              _Float16* __restrict__ W4h, _Float16* __restrict__ Wphi,
              _Float16* __restrict__ Wplo) {
    const int bid = blockIdx.x;
    const int tid = threadIdx.x;
    if (bid < 4096) {
        const size_t t = (size_t)bid * 256 + tid;
        const float4 v = ((const float4*)X)[t];
        half4 h;
        h.x = (_Float16)v.x; h.y = (_Float16)v.y;
        h.z = (_Float16)v.z; h.w = (_Float16)v.w;
        ((half4*)Xh)[t] = h;
    } else if (bid < 5120) {
        const int t = (bid - 4096) * 256 + tid;      // x_proj: N=1024, LOGN=10
        const int j  = t & 7;
        const int n  = (t >> 3) & 1023;
        const int q  = (t >> 13) & 3;
        const int kb = t >> 15;
        const int k  = kb * 32 + q * 8 + j;
        W1h[t] = (_Float16)Wx[(size_t)k * 1024 + n];
    } else if (bid < 5632) {
        const int t = (bid - 5120) * 256 + tid;      // out_proj: N=256, LOGN=8
        const int j  = t & 7;
        const int n  = (t >> 3) & 255;
        const int q  = (t >> 11) & 3;
        const int kb = t >> 13;
        const int k  = kb * 32 + q * 8 + j;
        W4h[t] = (_Float16)Wo[(size_t)k * 256 + n];
    } else {
        const int t = (bid - 5632) * 256 + tid;      // proj weights, N=64
        const int n  = (t >> 3) & 63;
        const int q  = (t >> 9) & 3;
        const int kb = t >> 11;
        const int k  = kb * 32 + q * 8 + (t & 7);
        float v;
        if      (n < 16) v = Wdt[(size_t)k * 16 + n];
        else if (n < 32) v = Wb [(size_t)k * 16 + (n - 16)];
        else if (n < 48) v = Wc [(size_t)k * 16 + (n - 32)];
        else             v = 0.f;
        const _Float16 hi = (_Float16)v;
        Wphi[t] = hi;
        Wplo[t] = (_Float16)(v - (float)hi);
    }
}

// ---------------------------------------------------------------------------
// K1: single-product fp16 MFMA GEMM, NO LDS. 1-D grid of 1024, XCD-swizzled:
// by = bid & 127, bx = bid >> 7 -> all 8 n-blocks of one m-block differ by
// multiples of 128 (= 0 mod 8) so they land on ONE XCD; A-rows hit that
// XCD's L2 (1 MB working set < 4 MB). silu -> fp16 U / G.
// ---------------------------------------------------------------------------
__global__ __launch_bounds__(256)
void mfma_gemm1(const _Float16* __restrict__ Ah, const _Float16* __restrict__ Wh,
                _Float16* __restrict__ O1, _Float16* __restrict__ O2) {
    const int KT = 256, NT = 1024;
    const int bid = blockIdx.x;
    const int by = bid & 127;      // m-tile (XCD = by % 8 for all bx)
    const int bx = bid >> 7;       // n-tile 0..7
    const int tid = threadIdx.x;
    const int lane = tid & 63;
    const int w  = tid >> 6;
    const int wm = w >> 1, wn = w & 1;
    const int n0 = bx * 128;
    const int m0 = by * 128;
    const int l15 = lane & 15, q = lane >> 4;

    floatx4 acc[4][4];
    const floatx4 zero = {0.f, 0.f, 0.f, 0.f};
    #pragma unroll
    for (int i = 0; i < 4; i++)
        #pragma unroll
        for (int j = 0; j < 4; j++) acc[i][j] = zero;

    const _Float16* aBase = Ah + (size_t)(m0 + wm * 64 + l15) * KT + q * 8;

    for (int kb = 0; kb < KT / 32; kb++) {
        half8 b[4], a[4];
        #pragma unroll
        for (int mt = 0; mt < 4; mt++)
            a[mt] = *(const half8*)(aBase + (size_t)(mt * 16) * KT + kb * 32);
        #pragma unroll
        for (int nt = 0; nt < 4; nt++) {
            const size_t off =
                ((size_t)((kb * 4 + q) * NT) + n0 + wn * 64 + nt * 16 + l15) * 8;
            b[nt] = *(const half8*)(Wh + off);
        }
        #pragma unroll
        for (int mt = 0; mt < 4; mt++)
            #pragma unroll
            for (int nt = 0; nt < 4; nt++)
                acc[mt][nt] = __builtin_amdgcn_mfma_f32_16x16x32_f16(
                    a[mt], b[nt], acc[mt][nt], 0, 0, 0);
    }
    // epilogue: D col=lane&15, row=quad*4+reg  [verified m89/m91; dtype-indep]
    #pragma unroll
    for (int mt = 0; mt < 4; mt++) {
        #pragma unroll
        for (int nt = 0; nt < 4; nt++) {
            const int col = n0 + wn * 64 + nt * 16 + l15;
            #pragma unroll
            for (int r = 0; r < 4; r++) {
                const int row = m0 + wm * 64 + mt * 16 + q * 4 + r;
                float v = acc[mt][nt][r];
                v = v / (1.f + __expf(-v));
                if (col < DINNER) O1[(size_t)row * DINNER + col] = (_Float16)v;
                else              O2[(size_t)row * DINNER + col - DINNER] = (_Float16)v;
            }
        }
    }
}

// ---------------------------------------------------------------------------
// K4: single-product fp16 MFMA GEMM, NO LDS. 1-D grid of 512, XCD-swizzled
// (by = bid & 127, bx = bid >> 7). Out fp32.
// ---------------------------------------------------------------------------
__global__ __launch_bounds__(256)
void mfma_gemm4(const _Float16* __restrict__ Ah, const _Float16* __restrict__ Wh,
                float* __restrict__ Out) {
    const int KT = 512, NT = 256;
    const int bid = blockIdx.x;
    const int by = bid & 127;
    const int bx = bid >> 7;       // 0..3
    const int tid = threadIdx.x;
    const int lane = tid & 63;
    const int w  = tid >> 6;
    const int wm = w >> 1, wn = w & 1;
    const int n0 = bx * 64;
    const int m0 = by * 128;
    const int l15 = lane & 15, q = lane >> 4;

    floatx4 acc[4][2];
    const floatx4 zero = {0.f, 0.f, 0.f, 0.f};
    #pragma unroll
    for (int i = 0; i < 4; i++)
        #pragma unroll
        for (int j = 0; j < 2; j++) acc[i][j] = zero;

    const _Float16* aBase = Ah + (size_t)(m0 + wm * 64 + l15) * KT + q * 8;

    for (int kb = 0; kb < KT / 32; kb++) {
        half8 b[2], a[4];
        #pragma unroll
        for (int mt = 0; mt < 4; mt++)
            a[mt] = *(const half8*)(aBase + (size_t)(mt * 16) * KT + kb * 32);
        #pragma unroll
        for (int nt = 0; nt < 2; nt++) {
            const size_t off =
                ((size_t)((kb * 4 + q) * NT) + n0 + wn * 32 + nt * 16 + l15) * 8;
            b[nt] = *(const half8*)(Wh + off);
        }
        #pragma unroll
        for (int mt = 0; mt < 4; mt++)
            #pragma unroll
            for (int nt = 0; nt < 2; nt++)
                acc[mt][nt] = __builtin_amdgcn_mfma_f32_16x16x32_f16(
                    a[mt], b[nt], acc[mt][nt], 0, 0, 0);
    }
    #pragma unroll
    for (int mt = 0; mt < 4; mt++) {
        #pragma unroll
        for (int nt = 0; nt < 2; nt++) {
            const int col = n0 + wn * 32 + nt * 16 + l15;
            #pragma unroll
            for (int r = 0; r < 4; r++) {
                const int row = m0 + wm * 64 + mt * 16 + q * 4 + r;
                Out[(size_t)row * NT + col] = acc[mt][nt][r];
            }
        }
    }
}

// ---------------------------------------------------------------------------
// proj_mfma (2-product, NO LDS): U fp16 @ Wp (512x64 hi/lo; 48 real cols) ->
// DT (softplus+bias) / BM / CM. 256 blocks x 64 rows.
// ---------------------------------------------------------------------------
__global__ __launch_bounds__(256)
void proj_mfma(const _Float16* __restrict__ Uh,
               const _Float16* __restrict__ Whi, const _Float16* __restrict__ Wlo,
               const float* __restrict__ bias,
               float* __restrict__ DT, float* __restrict__ BM,
               float* __restrict__ CM) {
    const int tid = threadIdx.x;
    const int lane = tid & 63;
    const int w  = tid >> 6;
    const int wm = w >> 1, wn = w & 1;
    const int m0 = blockIdx.x * 64;
    const int l15 = lane & 15, q = lane >> 4;

    floatx4 acc[2][2];
    const floatx4 zero = {0.f, 0.f, 0.f, 0.f};
    #pragma unroll
    for (int i = 0; i < 2; i++)
        #pragma unroll
        for (int j = 0; j < 2; j++) acc[i][j] = zero;

    const _Float16* aBase = Uh + (size_t)(m0 + wm * 32 + l15) * DINNER + q * 8;

    for (int kb = 0; kb < DINNER / 32; kb++) {
        half8 bh[2], bl[2], a[2];
        #pragma unroll
        for (int mt = 0; mt < 2; mt++)
            a[mt] = *(const half8*)(aBase + (size_t)(mt * 16) * DINNER + kb * 32);
        #pragma unroll
        for (int nt = 0; nt < 2; nt++) {
            const size_t off =
                ((size_t)((kb * 4 + q) * 64) + wn * 32 + nt * 16 + l15) * 8;
            bh[nt] = *(const half8*)(Whi + off);
            bl[nt] = *(const half8*)(Wlo + off);
        }
        #pragma unroll
        for (int mt = 0; mt < 2; mt++)
            #pragma unroll
            for (int nt = 0; nt < 2; nt++) {
                acc[mt][nt] = __builtin_amdgcn_mfma_f32_16x16x32_f16(
                    a[mt], bh[nt], acc[mt][nt], 0, 0, 0);
                acc[mt][nt] = __builtin_amdgcn_mfma_f32_16x16x32_f16(
                    a[mt], bl[nt], acc[mt][nt], 0, 0, 0);
            }
    }
    #pragma unroll
    for (int mt = 0; mt < 2; mt++) {
        #pragma unroll
        for (int nt = 0; nt < 2; nt++) {
            const int col = wn * 32 + nt * 16 + l15;
            #pragma unroll
            for (int r = 0; r < 4; r++) {
                const int row = m0 + wm * 32 + mt * 16 + q * 4 + r;
                float v = acc[mt][nt][r];
                if (col < 16) {
                    float dv = v + bias[col];
                    dv = (dv > 20.f) ? dv : log1pf(__expf(dv));
                    DT[(size_t)row * 16 + col] = dv;
                } else if (col < 32) {
                    BM[(size_t)row * 16 + (col - 16)] = v;
                } else if (col < 48) {
                    CM[(size_t)row * 16 + (col - 32)] = v;
                }
            }
        }
    }
}

// ---------------------------------------------------------------------------
// K3a: chunked scan phase A (CHUNK=32, 1024 blocks). One thread per d;
// states in floatx4[4]; LDS read as b128.
// ---------------------------------------------------------------------------
__global__ __launch_bounds__(256)
void scan_phase_a(const float* __restrict__ DT, const float* __restrict__ BM,
                  const _Float16* __restrict__ Uh,
                  const float* __restrict__ Alog,
                  float* __restrict__ HEND, float* __restrict__ PPROD) {
    __shared__ floatx4 sdt4[CHUNK * 4];
    __shared__ floatx4 sdb4[CHUNK * 4];
    const int tid = threadIdx.x;
    const int chunk = blockIdx.x;
    const int dg = blockIdx.y;
    const int b  = blockIdx.z;
    const int d  = dg*256 + tid;
    const int l0 = chunk * CHUNK;
    if (tid < CHUNK * 4) {
        const floatx4 dtv = ((const floatx4*)(DT + (size_t)(b*SEQLEN + l0)*16))[tid];
        const floatx4 bmv = ((const floatx4*)(BM + (size_t)(b*SEQLEN + l0)*16))[tid];
        sdt4[tid] = dtv;
        sdb4[tid] = dtv * bmv;
    }
    __syncthreads();
    floatx4 A4[4];
    #pragma unroll
    for (int qq = 0; qq < 4; qq++) {
        const floatx4 av = ((const floatx4*)(Alog + (size_t)d*16))[qq];
        A4[qq].x = -__expf(av.x); A4[qq].y = -__expf(av.y);
        A4[qq].z = -__expf(av.z); A4[qq].w = -__expf(av.w);
    }
    floatx4 h4[4], P4[4];
    #pragma unroll
    for (int qq = 0; qq < 4; qq++) {
        h4[qq] = (floatx4){0.f, 0.f, 0.f, 0.f};
        P4[qq] = (floatx4){1.f, 1.f, 1.f, 1.f};
    }
    const _Float16* uhp = Uh + ((size_t)(b*SEQLEN + l0))*DINNER + d;
    #pragma unroll 4
    for (int l = 0; l < CHUNK; l++) {
        const float u = (float)uhp[(size_t)l*DINNER];
        #pragma unroll
        for (int qq = 0; qq < 4; qq++) {
            const floatx4 dtv = sdt4[l*4 + qq];
            const floatx4 dbv = sdb4[l*4 + qq];
            floatx4 dA;
            dA.x = __expf(dtv.x * A4[qq].x);
            dA.y = __expf(dtv.y * A4[qq].y);
            dA.z = __expf(dtv.z * A4[qq].z);
            dA.w = __expf(dtv.w * A4[qq].w);
            h4[qq] = dA * h4[qq] + dbv * u;
            P4[qq] *= dA;
        }
    }
    floatx4* he = (floatx4*)(HEND  + ((size_t)(b*NCHUNK + chunk)*DINNER + d)*16);
    floatx4* pp = (floatx4*)(PPROD + ((size_t)(b*NCHUNK + chunk)*DINNER + d)*16);
    #pragma unroll
    for (int qq = 0; qq < 4; qq++) {
        he[qq] = h4[qq];
        pp[qq] = P4[qq];
    }
}

// ---------------------------------------------------------------------------
// K3b: sequential chain over 128 chunks. Thread per (b,d,s) = 32768.
// ---------------------------------------------------------------------------
__global__ __launch_bounds__(256)
void scan_phase_b(const float* __restrict__ HEND, const float* __restrict__ PPROD,
                  float* __restrict__ H0) {
    const int tid = threadIdx.x;
    const int s  = tid & 15;
    const int dl = tid >> 4;
    const int blk = blockIdx.x;
    const int b  = blk >> 5;
    const int dg = blk & 31;
    const int d  = dg*16 + dl;
    float h = 0.f;
    for (int c0 = 0; c0 < NCHUNK; c0 += 8) {
        float Pv[8], Hv[8];
        #pragma unroll
        for (int j = 0; j < 8; j++) {
            const size_t idx = ((size_t)(b*NCHUNK + c0 + j)*DINNER + d)*16 + s;
            Pv[j] = PPROD[idx];
            Hv[j] = HEND [idx];
        }
        #pragma unroll
        for (int j = 0; j < 8; j++) {
            H0[((size_t)(b*NCHUNK + c0 + j)*DINNER + d)*16 + s] = h;
            h = Pv[j]*h + Hv[j];
        }
    }
}

// ---------------------------------------------------------------------------
// K3c: rerun chunks from true initial state (CHUNK=32, 1024 blocks).
// floatx4 states, b128 LDS reads; emit Y2 fp16 fused with skip+gate.
// ---------------------------------------------------------------------------
__global__ __launch_bounds__(256)
void scan_phase_c(const float* __restrict__ DT, const float* __restrict__ BM,
                  const float* __restrict__ CM,
                  const _Float16* __restrict__ Uh, const _Float16* __restrict__ Gh,
                  const float* __restrict__ Alog,
                  const float* __restrict__ Dvec, const float* __restrict__ H0,
                  _Float16* __restrict__ Y2) {
    __shared__ floatx4 sdt4[CHUNK * 4];
    __shared__ floatx4 sdb4[CHUNK * 4];
    __shared__ floatx4 sc4 [CHUNK * 4];
    const int tid = threadIdx.x;
    const int chunk = blockIdx.x;
    const int dg = blockIdx.y;
    const int b  = blockIdx.z;
    const int d  = dg*256 + tid;
    const int l0 = chunk * CHUNK;
    if (tid < CHUNK * 4) {
        const floatx4 dtv = ((const floatx4*)(DT + (size_t)(b*SEQLEN + l0)*16))[tid];
        const floatx4 bmv = ((const floatx4*)(BM + (size_t)(b*SEQLEN + l0)*16))[tid];
        sdt4[tid] = dtv;
        sdb4[tid] = dtv * bmv;
    } else {
        const int t2 = tid - CHUNK * 4;
        sc4[t2] = ((const floatx4*)(CM + (size_t)(b*SEQLEN + l0)*16))[t2];
    }
    __syncthreads();
    floatx4 A4[4];
    #pragma unroll
    for (int qq = 0; qq < 4; qq++) {
        const floatx4 av = ((const floatx4*)(Alog + (size_t)d*16))[qq];
        A4[qq].x = -__expf(av.x); A4[qq].y = -__expf(av.y);
        A4[qq].z = -__expf(av.z); A4[qq].w = -__expf(av.w);
    }
    floatx4 h4[4];
    {
        const floatx4* h0 = (const floatx4*)(H0 +
            ((size_t)(b*NCHUNK + chunk)*DINNER + d)*16);
        #pragma unroll
        for (int qq = 0; qq < 4; qq++) h4[qq] = h0[qq];
    }
    const float Dd = Dvec[d];
    const size_t base = ((size_t)(b*SEQLEN + l0))*DINNER + d;
    const _Float16* uhp = Uh + base;
    const _Float16* ghp = Gh + base;
    _Float16* yp = Y2 + base;
    #pragma unroll 4
    for (int l = 0; l < CHUNK; l++) {
        const float u = (float)uhp[(size_t)l*DINNER];
        const float g = (float)ghp[(size_t)l*DINNER];
        floatx4 y4 = {0.f, 0.f, 0.f, 0.f};
        #pragma unroll
        for (int qq = 0; qq < 4; qq++) {
            const floatx4 dtv = sdt4[l*4 + qq];
            const floatx4 dbv = sdb4[l*4 + qq];
            const floatx4 cv  = sc4 [l*4 + qq];
            floatx4 dA;
            dA.x = __expf(dtv.x * A4[qq].x);
            dA.y = __expf(dtv.y * A4[qq].y);
            dA.z = __expf(dtv.z * A4[qq].z);
            dA.w = __expf(dtv.w * A4[qq].w);
            h4[qq] = dA * h4[qq] + dbv * u;
            y4 += h4[qq] * cv;
        }
        const float y = y4.x + y4.y + y4.z + y4.w;
        yp[(size_t)l*DINNER] = (_Float16)((y + u*Dd) * g);
    }
}

// ---------------------------------------------------------------------------
extern "C" void kernel_launch(void* const* d_in, const int* in_sizes, int n_in,
                              void* d_out, int out_size, void* d_ws, size_t ws_size,
                              hipStream_t stream) {
    const float* x        = (const float*)d_in[0];
    const float* x_proj   = (const float*)d_in[1];
    const float* dt_proj  = (const float*)d_in[2];
    const float* A_log    = (const float*)d_in[3];
    const float* B_proj   = (const float*)d_in[4];
    const float* C_proj   = (const float*)d_in[5];
    const float* Dvec     = (const float*)d_in[6];
    const float* out_proj = (const float*)d_in[7];
    const float* dt_bias  = (const float*)d_in[8];
    float* out = (float*)d_out;

    float* ws = (float*)d_ws;
    float* DT   = ws;                                    // 16384*16
    float* BM   = DT   + (size_t)M_ROWS*DSTATE;
    float* CM   = BM   + (size_t)M_ROWS*DSTATE;
    float* HEND = CM   + (size_t)M_ROWS*DSTATE;          // [b][chunk][d][s]
    float* PPRO = HEND + (size_t)BATCH*NCHUNK*DINNER*DSTATE;
    float* H0   = PPRO + (size_t)BATCH*NCHUNK*DINNER*DSTATE;
    _Float16* Y2   = (_Float16*)(H0 + (size_t)BATCH*NCHUNK*DINNER*DSTATE);
    _Float16* W1h  = Y2   + (size_t)M_ROWS*DINNER;
    _Float16* W4h  = W1h  + (size_t)NDIM*1024;
    _Float16* Wphi = W4h  + (size_t)DINNER*NDIM;         // 32768 each
    _Float16* Wplo = Wphi + (size_t)32768;
    _Float16* Uh   = Wplo + (size_t)32768;               // 16384*512
    _Float16* Gh   = Uh   + (size_t)M_ROWS*DINNER;
    // Xh aliases Y2: X consumed by K1 before scan_c writes Y2 (stream order).
    _Float16* Xh   = Y2;

    prep_all<<<dim3(5760), 256, 0, stream>>>(x, x_proj, out_proj, dt_proj,
                                             B_proj, C_proj,
                                             Xh, W1h, W4h, Wphi, Wplo);
    mfma_gemm1<<<dim3(1024), 256, 0, stream>>>(Xh, W1h, Uh, Gh);
    proj_mfma<<<dim3(M_ROWS/64), 256, 0, stream>>>(Uh, Wphi, Wplo,
                                                   dt_bias, DT, BM, CM);
    scan_phase_a<<<dim3(NCHUNK, DINNER/256, BATCH), 256, 0, stream>>>(
        DT, BM, Uh, A_log, HEND, PPRO);
    scan_phase_b<<<dim3(128), 256, 0, stream>>>(HEND, PPRO, H0);
    scan_phase_c<<<dim3(NCHUNK, DINNER/256, BATCH), 256, 0, stream>>>(
        DT, BM, CM, Uh, Gh, A_log, Dvec, H0, Y2);
    mfma_gemm4<<<dim3(512), 256, 0, stream>>>(Y2, W4h, out);
}